// Round 3
// baseline (1521.930 us; speedup 1.0000x reference)
//
#include <hip/hip_runtime.h>
#include <math.h>

// Problem constants (B=2, T=2048, DIM=2048, HEADS=16, HEAD_DIM=128, N_KV=4,
// LATENT=512, SEL_TOPK=64, SEL_DIM=64, SOFTCAP=30, EPS=1e-6)
#define T_SEQ 2048
#define BATCH 2
#define NHEADS 16
#define HD 128
#define NKV 4

typedef __bf16 bf16x8 __attribute__((ext_vector_type(8)));
typedef float f32x4 __attribute__((ext_vector_type(4)));

__device__ inline unsigned short bf16rne(float f) {
  unsigned u = __float_as_uint(f);
  unsigned r = (u + 0x7FFFu + ((u >> 16) & 1u)) >> 16;
  return (unsigned short)r;
}

__device__ inline void gload_lds16(const void* g, void* l) {
  __builtin_amdgcn_global_load_lds(
      (__attribute__((address_space(1))) void*)const_cast<void*>(g),
      (__attribute__((address_space(3))) void*)l, 16, 0, 0);
}

// monotonic encoding: enc(a) < enc(b) <=> a < b (floats, -inf ok)
#define ENC_NEGINF 0x007FFFFFu
__device__ inline unsigned enc32(float v) {
  unsigned u = __float_as_uint(v);
  return (u & 0x80000000u) ? ~u : (u | 0x80000000u);
}

// ---------------------------------------------------------------------------
// RoPE table: tab[t][i] = (cos, sin), i = pair index 0..63. numpy fp32 op
// order: y=fl32(10000^x) (double pow), inv=1/y (fp32), angle=fl32(t*inv).
// ---------------------------------------------------------------------------
__global__ void rope_table_kernel(float* __restrict__ tab) {
  int t = blockIdx.x;
  int i = threadIdx.x;                 // 0..63
  int j = (2 * i) & 63;
  float y = (float)pow(10000.0, (double)j / 64.0);
  float invf = 1.0f / y;
  float angle = (float)t * invf;
  double a = (double)angle;
  tab[(t * 64 + i) * 2 + 0] = (float)cos(a);
  tab[(t * 64 + i) * 2 + 1] = (float)sin(a);
}

// ---------------------------------------------------------------------------
// RMSNorm (128 dims) + interleaved RoPE, in place.
// ---------------------------------------------------------------------------
__global__ __launch_bounds__(128) void norm_rope_kernel(
    float* __restrict__ base, const float* __restrict__ w,
    const float* __restrict__ tab, int Hloc, int rowStride) {
  int blk = blockIdx.x;
  int h = blk % Hloc;
  int bt = blk / Hloc;
  int t = bt & (T_SEQ - 1);
  float* row = base + (size_t)bt * rowStride + h * HD;
  int d = threadIdx.x;
  float v = row[d];
  __shared__ float red[128];
  red[d] = v * v;
  __syncthreads();
#pragma unroll
  for (int off = 64; off > 0; off >>= 1) {
    if (d < off) red[d] += red[d + off];
    __syncthreads();
  }
  float ssum = red[0];
  __syncthreads();
  float inv = 1.0f / sqrtf(ssum / 128.0f + 1e-6f);
  float xn = v * inv * w[d];
  red[d] = xn;
  __syncthreads();
  int p = d >> 1;
  float c  = tab[(t * 64 + p) * 2 + 0];
  float sn = tab[(t * 64 + p) * 2 + 1];
  float x1 = red[p * 2], x2 = red[p * 2 + 1];
  row[d] = ((d & 1) == 0) ? (x1 * c - x2 * sn) : (x1 * sn + x2 * c);
}

// ---------------------------------------------------------------------------
// fp32 tiled GEMM (exact paths only: qsel head0, dlat, kv cols 0..127):
// C[M,N] = A[M,K] @ W[K,N] + bias. 64x64 tile, BK=16, 4x4 microtile.
// Sequential-k summation order (selection-exactness frozen since round 1).
// ---------------------------------------------------------------------------
#define BKG 16
__global__ __launch_bounds__(256) void sgemm_kernel(
    const float* __restrict__ A, const float* __restrict__ W,
    const float* __restrict__ bias, float* __restrict__ C,
    int M, int N, int K, int ldw, int ldc) {
  __shared__ float As[BKG][68];
  __shared__ float Bs[BKG][68];
  int tid = threadIdx.x;
  int tx = tid & 15;
  int ty = tid >> 4;
  int m0 = blockIdx.y * 64;
  int n0 = blockIdx.x * 64;
  int ar = tid >> 2, ac = (tid & 3) * 4;
  int brr = tid >> 4, bc = (tid & 15) * 4;
  const float* Ap = A + (size_t)(m0 + ar) * K + ac;
  const float* Wp = W + (size_t)brr * ldw + n0 + bc;
  float acc[4][4] = {};
  for (int k0 = 0; k0 < K; k0 += BKG) {
    float4 av = *(const float4*)(Ap + k0);
    float4 wv = *(const float4*)(Wp + (size_t)k0 * ldw);
    As[ac + 0][ar] = av.x; As[ac + 1][ar] = av.y;
    As[ac + 2][ar] = av.z; As[ac + 3][ar] = av.w;
    *(float4*)&Bs[brr][bc] = wv;
    __syncthreads();
#pragma unroll
    for (int kk = 0; kk < BKG; kk++) {
      float4 a = *(const float4*)&As[kk][ty * 4];
      float4 b = *(const float4*)&Bs[kk][tx * 4];
      float aa[4] = {a.x, a.y, a.z, a.w};
      float bb[4] = {b.x, b.y, b.z, b.w};
#pragma unroll
      for (int i = 0; i < 4; i++)
#pragma unroll
        for (int j = 0; j < 4; j++) acc[i][j] += aa[i] * bb[j];
    }
    __syncthreads();
  }
  float4 bv = *(const float4*)&bias[n0 + tx * 4];
  float bb[4] = {bv.x, bv.y, bv.z, bv.w};
#pragma unroll
  for (int i = 0; i < 4; i++) {
    float4 o;
    o.x = acc[i][0] + bb[0];
    o.y = acc[i][1] + bb[1];
    o.z = acc[i][2] + bb[2];
    o.w = acc[i][3] + bb[3];
    *(float4*)&C[(size_t)(m0 + ty * 4 + i) * ldc + n0 + tx * 4] = o;
  }
}

// ---------------------------------------------------------------------------
// bf16 MFMA GEMM: C[M,N] = A[M,K] @ BT[N,K]^T + bias, fp32 accumulate.
// 128x128 tile, BK=64, 4 waves, 16x16x32 MFMA. Fragment-major LDS so
// global_load_lds(16B) stages fragments directly; ds_read_b128 conflict-free.
// ---------------------------------------------------------------------------
__global__ __launch_bounds__(256) void mfma_gemm_bt(
    const unsigned short* __restrict__ A,   // [M,K] bf16
    const unsigned short* __restrict__ BT,  // [N,K] bf16
    const float* __restrict__ bias,         // [N]
    float* __restrict__ C,                  // [M,N] fp32
    int M, int N, int K) {
  __shared__ bf16x8 lA[16][64];
  __shared__ bf16x8 lB[16][64];
  int tid = threadIdx.x;
  int w = tid >> 6, lane = tid & 63;
  int m0 = blockIdx.y * 128, n0 = blockIdx.x * 128;
  int wm = w >> 1, wn = w & 1;
  f32x4 acc[4][4] = {};
  int sr = lane & 15;
  int sk = (lane >> 4) * 8;
  const unsigned short* Abase = A + (size_t)(m0 + sr) * K + sk;
  const unsigned short* Bbase = BT + (size_t)(n0 + sr) * K + sk;

  for (int k0 = 0; k0 < K; k0 += 64) {
    __syncthreads();
#pragma unroll
    for (int c = 0; c < 4; c++) {
      int ch = w * 4 + c;
      int tt = ch >> 1, kk = ch & 1;
      gload_lds16(Abase + (size_t)(tt * 16) * K + k0 + kk * 32, &lA[ch][0]);
      gload_lds16(Bbase + (size_t)(tt * 16) * K + k0 + kk * 32, &lB[ch][0]);
    }
    __syncthreads();
#pragma unroll
    for (int kk = 0; kk < 2; kk++) {
      bf16x8 af[4], bfr[4];
#pragma unroll
      for (int t = 0; t < 4; t++) {
        af[t]  = lA[(wm * 4 + t) * 2 + kk][lane];
        bfr[t] = lB[(wn * 4 + t) * 2 + kk][lane];
      }
#pragma unroll
      for (int i = 0; i < 4; i++)
#pragma unroll
        for (int j = 0; j < 4; j++)
          acc[i][j] = __builtin_amdgcn_mfma_f32_16x16x32_bf16(
              af[i], bfr[j], acc[i][j], 0, 0, 0);
    }
  }
  int col0 = n0 + wn * 64 + (lane & 15);
  int row0 = m0 + wm * 64 + (lane >> 4) * 4;
#pragma unroll
  for (int j = 0; j < 4; j++) {
    float bv = bias[col0 + j * 16];
#pragma unroll
    for (int i = 0; i < 4; i++) {
#pragma unroll
      for (int r = 0; r < 4; r++)
        C[(size_t)(row0 + i * 16 + r) * N + col0 + j * 16] = acc[i][j][r] + bv;
    }
  }
}

// ---------------------------------------------------------------------------
// fp32 -> bf16 flat convert (RNE), 4 elems/thread.
// ---------------------------------------------------------------------------
__global__ __launch_bounds__(256) void convert_bf16_kernel(
    const float* __restrict__ X, unsigned short* __restrict__ Y, int n4) {
  int i = blockIdx.x * 256 + threadIdx.x;
  if (i >= n4) return;
  float4 v = ((const float4*)X)[i];
  ushort4 o;
  o.x = bf16rne(v.x); o.y = bf16rne(v.y);
  o.z = bf16rne(v.z); o.w = bf16rne(v.w);
  ((ushort4*)Y)[i] = o;
}

// ---------------------------------------------------------------------------
// fp32 [K,N] -> bf16 [N,K] transpose-convert, 32x32 LDS tile.
// ---------------------------------------------------------------------------
__global__ __launch_bounds__(256) void transpose_bf16_kernel(
    const float* __restrict__ W, unsigned short* __restrict__ WT,
    int K, int N) {
  __shared__ unsigned short t[32][33];
  int k0 = blockIdx.y * 32, n0 = blockIdx.x * 32;
  int tid = threadIdx.x;
#pragma unroll
  for (int i = 0; i < 4; i++) {
    int idx = tid + i * 256;
    int r = idx >> 5, c = idx & 31;
    t[c][r] = bf16rne(W[(size_t)(k0 + r) * N + n0 + c]);
  }
  __syncthreads();
#pragma unroll
  for (int i = 0; i < 4; i++) {
    int idx = tid + i * 256;
    int r = idx >> 5, c = idx & 31;
    WT[(size_t)(n0 + r) * K + k0 + c] = t[r][c];
  }
}

// ---------------------------------------------------------------------------
// k head-0 (post-norm) transpose: kT[d][b*T+c] = kv[(b*T+c)*1024 + d], d<64.
// Makes select's k loads coalesced (lane = column).
// ---------------------------------------------------------------------------
__global__ __launch_bounds__(256) void ktrans_kernel(
    const float* __restrict__ kv, float* __restrict__ kT) {
  __shared__ float t[64][65];
  int c0 = blockIdx.x * 64;
  int tid = threadIdx.x;
#pragma unroll
  for (int u = 0; u < 16; u++) {
    int idx = tid + u * 256;
    int r = idx >> 6, d = idx & 63;
    t[d][r] = kv[(size_t)(c0 + r) * 1024 + d];
  }
  __syncthreads();
#pragma unroll
  for (int u = 0; u < 16; u++) {
    int idx = tid + u * 256;
    int d = idx >> 6, r = idx & 63;
    kT[(size_t)d * 4096 + c0 + r] = t[d][r];
  }
}

// ---------------------------------------------------------------------------
// Selection v3: wave-per-row, threshold search. Phase 1: lane computes 32
// scores (cols c=i*64+lane, coalesced via kT; fp32 FMA order identical to
// rounds 1/2) -> encoded u32 in LDS. Phase 2: binary search (32 steps) on the
// encoding for the 64th-largest value; ballot-compaction emits strict-greater
// winners then smallest-index ties (== jax.lax.top_k tie order). Diagonal
// appended if absent. No 64-bit shuffles, no serial rescans.
// ---------------------------------------------------------------------------
__global__ __launch_bounds__(256) void select_topk_kernel(
    const float* __restrict__ qsel,   // [BT,128] fp32 (normed+roped head 0)
    const float* __restrict__ kT,     // [64][4096] fp32 (post-norm k head 0)
    int* __restrict__ sel_cnt, int* __restrict__ sel_idx) {
  int blk = blockIdx.x;              // B*T/4
  int b = blk >> 9;
  int r0 = (blk & 511) * 4;
  int tid = threadIdx.x;

  if (r0 < 64) {                     // rows 0..63: all causal keys selected
    for (int j = 0; j < 4; j++) {
      int r = r0 + j;
      int row = b * T_SEQ + r;
      if (tid == 0) sel_cnt[row] = r + 1;
      for (int c = tid; c <= r; c += 256) sel_idx[row * 66 + c] = c;
    }
    return;
  }

  __shared__ unsigned scu[4][2048];

  int wv = tid >> 6, lane = tid & 63;
  int rr = r0 + wv;
  int row = b * T_SEQ + rr;

  // q row (first 64 dims) into regs — wave-uniform loads
  const float* qp = qsel + (size_t)row * 128;
  float qreg[64];
#pragma unroll
  for (int i = 0; i < 16; i++)
    *(float4*)&qreg[i * 4] = *(const float4*)(qp + i * 4);

  int imax = rr >> 6;
  for (int i = 0; i < 32; i++) {     // rolled: small code
    int c = i * 64 + lane;
    unsigned ev = ENC_NEGINF;
    if (i <= imax) {
      const float* kp = kT + b * T_SEQ + c;
      float a = 0.f;
#pragma unroll
      for (int d = 0; d < 64; d++) a += qreg[d] * kp[(size_t)d * 4096];
      ev = (c <= rr) ? enc32(a * 0.125f) : ENC_NEGINF;
    }
    scu[wv][c] = ev;
  }
  __syncthreads();                   // (same-lane RAW; barrier for safety)

  unsigned e[32];
#pragma unroll
  for (int i = 0; i < 32; i++) e[i] = scu[wv][i * 64 + lane];

  // binary search: largest t with count(e >= t) >= 64  ->  t = 64th largest
  unsigned t = 0;
  for (int bit = 31; bit >= 0; --bit) {
    unsigned cand = t | (1u << bit);
    int cnt = 0;
#pragma unroll
    for (int i = 0; i < 32; i++) cnt += (e[i] >= cand) ? 1 : 0;
#pragma unroll
    for (int off = 1; off < 64; off <<= 1) cnt += __shfl_xor(cnt, off);
    if (cnt >= 64) t = cand;
  }

  unsigned long long below = (lane == 63) ? 0x7FFFFFFFFFFFFFFFull
                                          : ((1ull << lane) - 1ull);
  bool hasdiag = false;
  // pass A: strictly greater (count g < 64 guaranteed)
  int base = 0;
#pragma unroll
  for (int i = 0; i < 32; i++) {
    int c = i * 64 + lane;
    bool wn = (e[i] > t);
    unsigned long long m = __ballot(wn);
    if (wn) {
      int slot = base + (int)__popcll(m & below);
      sel_idx[(size_t)row * 66 + slot] = c;
      if (c == rr) hasdiag = true;
    }
    base += (int)__popcll(m);
  }
  int g = base;
  int need = 64 - g;
  // pass B: ties at t, ascending index, first `need`
  int tb = 0;
#pragma unroll
  for (int i = 0; i < 32; i++) {
    int c = i * 64 + lane;
    bool tie = (e[i] == t);
    unsigned long long m = __ballot(tie);
    int rank = tb + (int)__popcll(m & below);
    if (tie && rank < need) {
      sel_idx[(size_t)row * 66 + g + rank] = c;
      if (c == rr) hasdiag = true;
    }
    tb += (int)__popcll(m);
  }
  unsigned long long hd = __ballot(hasdiag);
  if (lane == 0) {
    sel_cnt[row] = hd ? 64 : 65;
    if (!hd) sel_idx[(size_t)row * 66 + 64] = rr;
  }
}

// ---------------------------------------------------------------------------
// Gathered attention (unchanged — passed rounds 1/2).
// ---------------------------------------------------------------------------
__global__ __launch_bounds__(256) void attn_kernel(
    const float* __restrict__ q, const float* __restrict__ kv,
    const int* __restrict__ sel_cnt, const int* __restrict__ sel_idx,
    float* __restrict__ yg) {
  int blk = blockIdx.x;
  int g = blk & 3;
  int br = blk >> 2;
  int b = br >> 11;
  int r = br & (T_SEQ - 1);
  int tid = threadIdx.x;
  int lane = tid & 63, wv = tid >> 6;

  __shared__ float ksT[128][67];
  __shared__ float qsh[4][128];
  __shared__ int idxs[66];

  int cnt = sel_cnt[br];
  if (tid < cnt) idxs[tid] = sel_idx[br * 66 + tid];
  for (int i = tid; i < 4 * 128; i += 256) {
    int h = i >> 7, d = i & 127;
    qsh[h][d] = q[((size_t)br * NHEADS + g * 4 + h) * HD + d];
  }
  __syncthreads();
  for (int i = tid; i < cnt * 32; i += 256) {
    int j = i >> 5, d4 = (i & 31) * 4;
    const float* kp = kv + (size_t)(b * T_SEQ + idxs[j]) * 1024 + g * HD + d4;
    float4 kd = *(const float4*)kp;
    ksT[d4 + 0][j] = kd.x; ksT[d4 + 1][j] = kd.y;
    ksT[d4 + 2][j] = kd.z; ksT[d4 + 3][j] = kd.w;
  }
  __syncthreads();

  int H = g * 4 + wv;
  double sd = 1.0;
  for (int i = 0; i <= H; i++) sd *= 0.70710678118654752440;
  float slope = (float)sd;

  float s0 = -INFINITY, s1 = -INFINITY;
  for (int jj = lane; jj < cnt; jj += 64) {
    float acc = 0.f;
#pragma unroll 8
    for (int d = 0; d < 128; d++) acc += qsh[wv][d] * ksT[d][jj];
    float sca = acc / sqrtf(128.0f);
    float tch = tanhf(sca / 30.0f) * 30.0f;
    float biasv = -slope * (float)(r - idxs[jj]);
    float val = tch + biasv;
    if (jj == lane) s0 = val; else s1 = val;
  }
  float m = fmaxf(s0, s1);
#pragma unroll
  for (int off = 32; off > 0; off >>= 1) m = fmaxf(m, __shfl_down(m, off));
  m = __shfl(m, 0);
  float e0 = (lane < cnt) ? expf(s0 - m) : 0.f;
  float e1 = (lane + 64 < cnt) ? expf(s1 - m) : 0.f;
  float sum = e0 + e1;
#pragma unroll
  for (int off = 32; off > 0; off >>= 1) sum += __shfl_down(sum, off);
  sum = __shfl(sum, 0);
  float p0 = e0 / sum;
  float p1 = e1 / sum;

  const float* vbase = kv + (size_t)b * T_SEQ * 1024 + 512 + g * HD;
  float y0 = 0.f, y1 = 0.f;
  for (int j = 0; j < cnt; j++) {
    float pj = (j < 64) ? __shfl(p0, j) : __shfl(p1, j - 64);
    const float* vp = vbase + (size_t)idxs[j] * 1024;
    y0 += pj * vp[lane];
    y1 += pj * vp[lane + 64];
  }
  float* op = yg + (size_t)br * 2048 + H * HD;
  op[lane] = y0;
  op[lane + 64] = y1;
}

// ---------------------------------------------------------------------------
// Gate (unchanged).
// ---------------------------------------------------------------------------
__global__ __launch_bounds__(256) void gate_kernel(
    float* __restrict__ yg, const float* __restrict__ gw,
    const float* __restrict__ gb) {
  int blk = blockIdx.x;
  int h = blk & 15;
  int bt0 = (blk >> 4) * 16;
  int tid = threadIdx.x;
  __shared__ float ys[16][128];
  for (int i = tid; i < 16 * 128; i += 256) {
    int rr = i >> 7, d = i & 127;
    ys[rr][d] = yg[(size_t)(bt0 + rr) * 2048 + h * HD + d];
  }
  __syncthreads();
  int e = tid & 127;
  int rblk = tid >> 7;
  const float* gwp = gw + (size_t)h * 16384 + e;
  float acc[8] = {};
  for (int d = 0; d < 128; d++) {
    float wval = gwp[(size_t)d * 128];
#pragma unroll
    for (int k = 0; k < 8; k++) acc[k] += ys[rblk * 8 + k][d] * wval;
  }
  float bb = gb[h * 128 + e];
#pragma unroll
  for (int k = 0; k < 8; k++) {
    int rr = rblk * 8 + k;
    float gate = 1.f / (1.f + expf(-(acc[k] + bb)));
    yg[(size_t)(bt0 + rr) * 2048 + h * HD + e] = ys[rr][e] * gate;
  }
}

// ---------------------------------------------------------------------------
extern "C" void kernel_launch(void* const* d_in, const int* in_sizes, int n_in,
                              void* d_out, int out_size, void* d_ws, size_t ws_size,
                              hipStream_t stream) {
  const float* x      = (const float*)d_in[0];
  const float* w_q    = (const float*)d_in[1];
  const float* b_q    = (const float*)d_in[2];
  const float* w_down = (const float*)d_in[3];
  const float* b_down = (const float*)d_in[4];
  const float* w_up   = (const float*)d_in[5];
  const float* b_up   = (const float*)d_in[6];
  const float* w_o    = (const float*)d_in[7];
  const float* b_o    = (const float*)d_in[8];
  const float* qn_w   = (const float*)d_in[9];
  const float* kn_w   = (const float*)d_in[10];
  const float* gate_w = (const float*)d_in[11];
  const float* gate_b = (const float*)d_in[12];

  // ws layout (float offsets):
  //   kvbuf 0 | yg/dlat 4194304 | tab 12582912 | cnt 12845056(int)
  //   sidx 12849152(int) | qsel 13120000 | kT 13644288 | [ushorts from
  //   13906432]: xb/dlatb/ygb (8.39M) then wT/wupT (4.19M)   (~81 MB)
  float* ws    = (float*)d_ws;
  float* kvbuf = ws;
  float* yg    = ws + 4194304;
  float* dlat  = yg;                          // dead before attn writes yg
  float* tab   = ws + 12582912;
  int*   cnt   = (int*)(ws + 12845056);
  int*   sidx  = cnt + 4096;
  float* qsel  = ws + 13120000;               // 4096 x 128
  float* kT    = ws + 13644288;               // 64 x 4096
  unsigned short* xb  = (unsigned short*)(ws + 13906432);  // 4096x2048 bf16
  unsigned short* dlatb = xb;                 // xb dead after q-proj
  unsigned short* ygb = xb;                   // dead again after up-proj
  unsigned short* wT  = xb + 8388608;         // 2048x2048 bf16 [N,K]
  unsigned short* wupT = wT;                  // w_qT dead after q-proj mfma

  float* qbuf = (float*)d_out;                // d_out doubles as q staging
  const int BT = BATCH * T_SEQ;               // 4096

  rope_table_kernel<<<T_SEQ, 64, 0, stream>>>(tab);
  // ---- q-proj (bf16 MFMA) ----
  convert_bf16_kernel<<<8192, 256, 0, stream>>>(x, xb, 2097152);
  transpose_bf16_kernel<<<dim3(64, 64), 256, 0, stream>>>(w_q, wT, 2048, 2048);
  mfma_gemm_bt<<<dim3(16, 32), 256, 0, stream>>>(xb, wT, b_q, qbuf,
                                                 BT, 2048, 2048);
  // ---- exact fp32 selection q: head 0 ----
  sgemm_kernel<<<dim3(2, 64), 256, 0, stream>>>(x, w_q, b_q, qsel,
                                                BT, 128, 2048, 2048, 128);
  // ---- latent down-proj (fp32 exact; feeds selection k) ----
  sgemm_kernel<<<dim3(8, 64), 256, 0, stream>>>(x, w_down, b_down, dlat,
                                                BT, 512, 2048, 512, 512);
  // ---- up-proj: full kv in bf16 MFMA, then exact fp32 cols 0..127 ----
  convert_bf16_kernel<<<2048, 256, 0, stream>>>(dlat, dlatb, 524288);
  transpose_bf16_kernel<<<dim3(32, 16), 256, 0, stream>>>(w_up, wupT,
                                                          512, 1024);
  mfma_gemm_bt<<<dim3(8, 32), 256, 0, stream>>>(dlatb, wupT, b_up, kvbuf,
                                                BT, 1024, 512);
  sgemm_kernel<<<dim3(2, 64), 256, 0, stream>>>(dlat, w_up, b_up, kvbuf,
                                                BT, 128, 512, 1024, 1024);
  // ---- rmsnorm + rope ----
  norm_rope_kernel<<<BT * 16, 128, 0, stream>>>(qbuf, qn_w, tab, 16, 2048);
  norm_rope_kernel<<<BT, 128, 0, stream>>>(qsel, qn_w, tab, 1, 128);
  norm_rope_kernel<<<BT * 4, 128, 0, stream>>>(kvbuf, kn_w, tab, 4, 1024);
  // ---- selection ----
  ktrans_kernel<<<BT / 64, 256, 0, stream>>>(kvbuf, kT);
  select_topk_kernel<<<BT / 4, 256, 0, stream>>>(qsel, kT, cnt, sidx);
  // ---- gathered sparse attention ----
  attn_kernel<<<BT * 4, 256, 0, stream>>>(qbuf, kvbuf, cnt, sidx, yg);
  // ---- gating ----
  gate_kernel<<<(BT / 16) * 16, 256, 0, stream>>>(yg, gate_w, gate_b);
  // ---- o-proj (bf16 MFMA) ----
  convert_bf16_kernel<<<8192, 256, 0, stream>>>(yg, ygb, 2097152);
  transpose_bf16_kernel<<<dim3(64, 64), 256, 0, stream>>>(w_o, wT, 2048, 2048);
  mfma_gemm_bt<<<dim3(16, 32), 256, 0, stream>>>(ygb, wT, b_o, (float*)d_out,
                                                 BT, 2048, 2048);
}

// Round 4
// 1067.668 us; speedup vs baseline: 1.4255x; 1.4255x over previous
//
#include <hip/hip_runtime.h>
#include <math.h>

// Problem constants (B=2, T=2048, DIM=2048, HEADS=16, HEAD_DIM=128, N_KV=4,
// LATENT=512, SEL_TOPK=64, SEL_DIM=64, SOFTCAP=30, EPS=1e-6)
#define T_SEQ 2048
#define BATCH 2
#define NHEADS 16
#define HD 128
#define NKV 4

typedef __bf16 bf16x8 __attribute__((ext_vector_type(8)));
typedef float f32x4 __attribute__((ext_vector_type(4)));

__device__ inline unsigned short bf16rne(float f) {
  unsigned u = __float_as_uint(f);
  unsigned r = (u + 0x7FFFu + ((u >> 16) & 1u)) >> 16;
  return (unsigned short)r;
}

__device__ inline void gload_lds16(const void* g, void* l) {
  __builtin_amdgcn_global_load_lds(
      (__attribute__((address_space(1))) void*)const_cast<void*>(g),
      (__attribute__((address_space(3))) void*)l, 16, 0, 0);
}

// monotonic encoding: enc(a) < enc(b) <=> a < b (floats, -inf ok)
#define ENC_NEGINF 0x007FFFFFu
__device__ inline unsigned enc32(float v) {
  unsigned u = __float_as_uint(v);
  return (u & 0x80000000u) ? ~u : (u | 0x80000000u);
}

// ---------------------------------------------------------------------------
// RoPE table: tab[t][i] = (cos, sin), i = pair index 0..63. numpy fp32 op
// order: y=fl32(10000^x) (double pow), inv=1/y (fp32), angle=fl32(t*inv).
// ---------------------------------------------------------------------------
__global__ void rope_table_kernel(float* __restrict__ tab) {
  int t = blockIdx.x;
  int i = threadIdx.x;                 // 0..63
  int j = (2 * i) & 63;
  float y = (float)pow(10000.0, (double)j / 64.0);
  float invf = 1.0f / y;
  float angle = (float)t * invf;
  double a = (double)angle;
  tab[(t * 64 + i) * 2 + 0] = (float)cos(a);
  tab[(t * 64 + i) * 2 + 1] = (float)sin(a);
}

// ---------------------------------------------------------------------------
// RMSNorm (128 dims) + interleaved RoPE, in place.
// ---------------------------------------------------------------------------
__global__ __launch_bounds__(128) void norm_rope_kernel(
    float* __restrict__ base, const float* __restrict__ w,
    const float* __restrict__ tab, int Hloc, int rowStride) {
  int blk = blockIdx.x;
  int h = blk % Hloc;
  int bt = blk / Hloc;
  int t = bt & (T_SEQ - 1);
  float* row = base + (size_t)bt * rowStride + h * HD;
  int d = threadIdx.x;
  float v = row[d];
  __shared__ float red[128];
  red[d] = v * v;
  __syncthreads();
#pragma unroll
  for (int off = 64; off > 0; off >>= 1) {
    if (d < off) red[d] += red[d + off];
    __syncthreads();
  }
  float ssum = red[0];
  __syncthreads();
  float inv = 1.0f / sqrtf(ssum / 128.0f + 1e-6f);
  float xn = v * inv * w[d];
  red[d] = xn;
  __syncthreads();
  int p = d >> 1;
  float c  = tab[(t * 64 + p) * 2 + 0];
  float sn = tab[(t * 64 + p) * 2 + 1];
  float x1 = red[p * 2], x2 = red[p * 2 + 1];
  row[d] = ((d & 1) == 0) ? (x1 * c - x2 * sn) : (x1 * sn + x2 * c);
}

// ---------------------------------------------------------------------------
// fp32 tiled GEMM (exact paths only: qsel head0, dlat, kv cols 0..127):
// C[M,N] = A[M,K] @ W[K,N] + bias. 64x64 tile, BK=16, 4x4 microtile.
// ---------------------------------------------------------------------------
#define BKG 16
__global__ __launch_bounds__(256) void sgemm_kernel(
    const float* __restrict__ A, const float* __restrict__ W,
    const float* __restrict__ bias, float* __restrict__ C,
    int M, int N, int K, int ldw, int ldc) {
  __shared__ float As[BKG][68];
  __shared__ float Bs[BKG][68];
  int tid = threadIdx.x;
  int tx = tid & 15;
  int ty = tid >> 4;
  int m0 = blockIdx.y * 64;
  int n0 = blockIdx.x * 64;
  int ar = tid >> 2, ac = (tid & 3) * 4;
  int brr = tid >> 4, bc = (tid & 15) * 4;
  const float* Ap = A + (size_t)(m0 + ar) * K + ac;
  const float* Wp = W + (size_t)brr * ldw + n0 + bc;
  float acc[4][4] = {};
  for (int k0 = 0; k0 < K; k0 += BKG) {
    float4 av = *(const float4*)(Ap + k0);
    float4 wv = *(const float4*)(Wp + (size_t)k0 * ldw);
    As[ac + 0][ar] = av.x; As[ac + 1][ar] = av.y;
    As[ac + 2][ar] = av.z; As[ac + 3][ar] = av.w;
    *(float4*)&Bs[brr][bc] = wv;
    __syncthreads();
#pragma unroll
    for (int kk = 0; kk < BKG; kk++) {
      float4 a = *(const float4*)&As[kk][ty * 4];
      float4 b = *(const float4*)&Bs[kk][tx * 4];
      float aa[4] = {a.x, a.y, a.z, a.w};
      float bb[4] = {b.x, b.y, b.z, b.w};
#pragma unroll
      for (int i = 0; i < 4; i++)
#pragma unroll
        for (int j = 0; j < 4; j++) acc[i][j] += aa[i] * bb[j];
    }
    __syncthreads();
  }
  float4 bv = *(const float4*)&bias[n0 + tx * 4];
  float bb[4] = {bv.x, bv.y, bv.z, bv.w};
#pragma unroll
  for (int i = 0; i < 4; i++) {
    float4 o;
    o.x = acc[i][0] + bb[0];
    o.y = acc[i][1] + bb[1];
    o.z = acc[i][2] + bb[2];
    o.w = acc[i][3] + bb[3];
    *(float4*)&C[(size_t)(m0 + ty * 4 + i) * ldc + n0 + tx * 4] = o;
  }
}

// ---------------------------------------------------------------------------
// bf16 MFMA GEMM: C[M,N] = A[M,K] @ BT[N,K]^T + bias, fp32 accumulate.
// 128x128 tile, BK=64, 4 waves, 16x16x32 MFMA. Fragment-major LDS so
// global_load_lds(16B) stages fragments directly; ds_read_b128 conflict-free.
// ---------------------------------------------------------------------------
__global__ __launch_bounds__(256) void mfma_gemm_bt(
    const unsigned short* __restrict__ A,   // [M,K] bf16
    const unsigned short* __restrict__ BT,  // [N,K] bf16
    const float* __restrict__ bias,         // [N]
    float* __restrict__ C,                  // [M,N] fp32
    int M, int N, int K) {
  __shared__ bf16x8 lA[16][64];
  __shared__ bf16x8 lB[16][64];
  int tid = threadIdx.x;
  int w = tid >> 6, lane = tid & 63;
  int m0 = blockIdx.y * 128, n0 = blockIdx.x * 128;
  int wm = w >> 1, wn = w & 1;
  f32x4 acc[4][4] = {};
  int sr = lane & 15;
  int sk = (lane >> 4) * 8;
  const unsigned short* Abase = A + (size_t)(m0 + sr) * K + sk;
  const unsigned short* Bbase = BT + (size_t)(n0 + sr) * K + sk;

  for (int k0 = 0; k0 < K; k0 += 64) {
    __syncthreads();
#pragma unroll
    for (int c = 0; c < 4; c++) {
      int ch = w * 4 + c;
      int tt = ch >> 1, kk = ch & 1;
      gload_lds16(Abase + (size_t)(tt * 16) * K + k0 + kk * 32, &lA[ch][0]);
      gload_lds16(Bbase + (size_t)(tt * 16) * K + k0 + kk * 32, &lB[ch][0]);
    }
    __syncthreads();
#pragma unroll
    for (int kk = 0; kk < 2; kk++) {
      bf16x8 af[4], bfr[4];
#pragma unroll
      for (int t = 0; t < 4; t++) {
        af[t]  = lA[(wm * 4 + t) * 2 + kk][lane];
        bfr[t] = lB[(wn * 4 + t) * 2 + kk][lane];
      }
#pragma unroll
      for (int i = 0; i < 4; i++)
#pragma unroll
        for (int j = 0; j < 4; j++)
          acc[i][j] = __builtin_amdgcn_mfma_f32_16x16x32_bf16(
              af[i], bfr[j], acc[i][j], 0, 0, 0);
    }
  }
  int col0 = n0 + wn * 64 + (lane & 15);
  int row0 = m0 + wm * 64 + (lane >> 4) * 4;
#pragma unroll
  for (int j = 0; j < 4; j++) {
    float bv = bias[col0 + j * 16];
#pragma unroll
    for (int i = 0; i < 4; i++) {
#pragma unroll
      for (int r = 0; r < 4; r++)
        C[(size_t)(row0 + i * 16 + r) * N + col0 + j * 16] = acc[i][j][r] + bv;
    }
  }
}

// ---------------------------------------------------------------------------
// fp32 -> bf16 flat convert (RNE), 4 elems/thread.
// ---------------------------------------------------------------------------
__global__ __launch_bounds__(256) void convert_bf16_kernel(
    const float* __restrict__ X, unsigned short* __restrict__ Y, int n4) {
  int i = blockIdx.x * 256 + threadIdx.x;
  if (i >= n4) return;
  float4 v = ((const float4*)X)[i];
  ushort4 o;
  o.x = bf16rne(v.x); o.y = bf16rne(v.y);
  o.z = bf16rne(v.z); o.w = bf16rne(v.w);
  ((ushort4*)Y)[i] = o;
}

// ---------------------------------------------------------------------------
// fp32 [K,N] -> bf16 [N,K] transpose-convert, 32x32 LDS tile.
// ---------------------------------------------------------------------------
__global__ __launch_bounds__(256) void transpose_bf16_kernel(
    const float* __restrict__ W, unsigned short* __restrict__ WT,
    int K, int N) {
  __shared__ unsigned short t[32][33];
  int k0 = blockIdx.y * 32, n0 = blockIdx.x * 32;
  int tid = threadIdx.x;
#pragma unroll
  for (int i = 0; i < 4; i++) {
    int idx = tid + i * 256;
    int r = idx >> 5, c = idx & 31;
    t[c][r] = bf16rne(W[(size_t)(k0 + r) * N + n0 + c]);
  }
  __syncthreads();
#pragma unroll
  for (int i = 0; i < 4; i++) {
    int idx = tid + i * 256;
    int r = idx >> 5, c = idx & 31;
    WT[(size_t)(n0 + r) * K + k0 + c] = t[r][c];
  }
}

// ---------------------------------------------------------------------------
// Selection scores: one 64x64 causal tile per block, per batch b.
// S[r][c] = enc32( (q[r,0:64] . k[c,0:64]) * 0.125 ) for c<=r, else NEGINF.
// q/k tiles staged transposed in LDS ([d][row], pad 68 keeps 16B align);
// 4x4 microtile, sequential d accumulation (same fp32 order as prior rounds).
// ---------------------------------------------------------------------------
__global__ __launch_bounds__(256) void score_kernel(
    const float* __restrict__ qsel,   // [BT,128] (normed+roped head 0)
    const float* __restrict__ kv,     // [BT,1024] (post-norm; k head0 = 0:64)
    unsigned* __restrict__ S,         // [2048][2048] for batch b
    int b) {
  int tc = blockIdx.x, tr = blockIdx.y;
  if (tc > tr || tr == 0) return;     // causal; rows 0..63 use early path
  __shared__ float qsT[64][68];
  __shared__ float ksT[64][68];
  int tid = threadIdx.x;
  int r0 = tr * 64, c0 = tc * 64;
#pragma unroll
  for (int u = 0; u < 16; u++) {
    int idx = u * 256 + tid;
    int row = idx >> 6, d = idx & 63;
    qsT[d][row] = qsel[((size_t)(b * T_SEQ + r0 + row)) * 128 + d];
  }
#pragma unroll
  for (int u = 0; u < 16; u++) {
    int idx = u * 256 + tid;
    int c = idx >> 6, d = idx & 63;
    ksT[d][c] = kv[((size_t)(b * T_SEQ + c0 + c)) * 1024 + d];
  }
  __syncthreads();
  int tx = tid & 15, ty = tid >> 4;
  float acc[4][4] = {};
  for (int d = 0; d < 64; d++) {
    float4 qv = *(const float4*)&qsT[d][ty * 4];
    float4 kx = *(const float4*)&ksT[d][tx * 4];
    float qq[4] = {qv.x, qv.y, qv.z, qv.w};
    float kk[4] = {kx.x, kx.y, kx.z, kx.w};
#pragma unroll
    for (int i = 0; i < 4; i++)
#pragma unroll
      for (int j = 0; j < 4; j++) acc[i][j] += qq[i] * kk[j];
  }
#pragma unroll
  for (int i = 0; i < 4; i++) {
    int r = r0 + ty * 4 + i;
    uint4 o;
    int c = c0 + tx * 4;
    o.x = (c + 0 <= r) ? enc32(acc[i][0] * 0.125f) : ENC_NEGINF;
    o.y = (c + 1 <= r) ? enc32(acc[i][1] * 0.125f) : ENC_NEGINF;
    o.z = (c + 2 <= r) ? enc32(acc[i][2] * 0.125f) : ENC_NEGINF;
    o.w = (c + 3 <= r) ? enc32(acc[i][3] * 0.125f) : ENC_NEGINF;
    *(uint4*)&S[(size_t)r * 2048 + c] = o;
  }
}

// ---------------------------------------------------------------------------
// Selection v4: wave-per-row from precomputed encoded scores. Binary search
// (32 steps) for the 64th-largest encoding; ballot-compaction emits
// strict-greater winners then smallest-index ties (jax.lax.top_k order).
// Zero LDS, ~48 VGPR. Per batch b; 4 rows per block.
// ---------------------------------------------------------------------------
__global__ __launch_bounds__(256) void select_topk_kernel(
    const unsigned* __restrict__ S,   // [2048][2048] batch b
    int* __restrict__ sel_cnt, int* __restrict__ sel_idx, int b) {
  int blk = blockIdx.x;              // 512 blocks of 4 rows
  int r0 = blk * 4;
  int tid = threadIdx.x;

  if (r0 < 64) {                     // rows 0..63: all causal keys selected
    for (int j = 0; j < 4; j++) {
      int r = r0 + j;
      int row = b * T_SEQ + r;
      if (tid == 0) sel_cnt[row] = r + 1;
      for (int c = tid; c <= r; c += 256) sel_idx[row * 66 + c] = c;
    }
    return;
  }

  int wv = tid >> 6, lane = tid & 63;
  int rr = r0 + wv;
  int row = b * T_SEQ + rr;
  int imax = rr >> 6;

  unsigned e[32];
  const unsigned* Sp = S + (size_t)rr * 2048 + lane;
#pragma unroll
  for (int i = 0; i < 32; i++) e[i] = (i <= imax) ? Sp[i * 64] : ENC_NEGINF;

  // binary search: largest t with count(e >= t) >= 64  ->  t = 64th largest
  unsigned t = 0;
  for (int bit = 31; bit >= 0; --bit) {
    unsigned cand = t | (1u << bit);
    int cnt = 0;
#pragma unroll
    for (int i = 0; i < 32; i++) cnt += (e[i] >= cand) ? 1 : 0;
#pragma unroll
    for (int off = 1; off < 64; off <<= 1) cnt += __shfl_xor(cnt, off);
    if (cnt >= 64) t = cand;
  }

  unsigned long long below = (lane == 63) ? 0x7FFFFFFFFFFFFFFFull
                                          : ((1ull << lane) - 1ull);
  bool hasdiag = false;
  // pass A: strictly greater (count g < 64 guaranteed)
  int base = 0;
#pragma unroll
  for (int i = 0; i < 32; i++) {
    int c = i * 64 + lane;
    bool wn = (e[i] > t);
    unsigned long long m = __ballot(wn);
    if (wn) {
      int slot = base + (int)__popcll(m & below);
      sel_idx[(size_t)row * 66 + slot] = c;
      if (c == rr) hasdiag = true;
    }
    base += (int)__popcll(m);
  }
  int g = base;
  int need = 64 - g;
  // pass B: ties at t, ascending index, first `need`
  int tb = 0;
#pragma unroll
  for (int i = 0; i < 32; i++) {
    int c = i * 64 + lane;
    bool tie = (e[i] == t);
    unsigned long long m = __ballot(tie);
    int rank = tb + (int)__popcll(m & below);
    if (tie && rank < need) {
      sel_idx[(size_t)row * 66 + g + rank] = c;
      if (c == rr) hasdiag = true;
    }
    tb += (int)__popcll(m);
  }
  unsigned long long hd = __ballot(hasdiag);
  if (lane == 0) {
    sel_cnt[row] = hd ? 64 : 65;
    if (!hd) sel_idx[(size_t)row * 66 + 64] = rr;
  }
}

// ---------------------------------------------------------------------------
// Gathered attention (unchanged — passed rounds 1-3).
// ---------------------------------------------------------------------------
__global__ __launch_bounds__(256) void attn_kernel(
    const float* __restrict__ q, const float* __restrict__ kv,
    const int* __restrict__ sel_cnt, const int* __restrict__ sel_idx,
    float* __restrict__ yg) {
  int blk = blockIdx.x;
  int g = blk & 3;
  int br = blk >> 2;
  int b = br >> 11;
  int r = br & (T_SEQ - 1);
  int tid = threadIdx.x;
  int lane = tid & 63, wv = tid >> 6;

  __shared__ float ksT[128][67];
  __shared__ float qsh[4][128];
  __shared__ int idxs[66];

  int cnt = sel_cnt[br];
  if (tid < cnt) idxs[tid] = sel_idx[br * 66 + tid];
  for (int i = tid; i < 4 * 128; i += 256) {
    int h = i >> 7, d = i & 127;
    qsh[h][d] = q[((size_t)br * NHEADS + g * 4 + h) * HD + d];
  }
  __syncthreads();
  for (int i = tid; i < cnt * 32; i += 256) {
    int j = i >> 5, d4 = (i & 31) * 4;
    const float* kp = kv + (size_t)(b * T_SEQ + idxs[j]) * 1024 + g * HD + d4;
    float4 kd = *(const float4*)kp;
    ksT[d4 + 0][j] = kd.x; ksT[d4 + 1][j] = kd.y;
    ksT[d4 + 2][j] = kd.z; ksT[d4 + 3][j] = kd.w;
  }
  __syncthreads();

  int H = g * 4 + wv;
  double sd = 1.0;
  for (int i = 0; i <= H; i++) sd *= 0.70710678118654752440;
  float slope = (float)sd;

  float s0 = -INFINITY, s1 = -INFINITY;
  for (int jj = lane; jj < cnt; jj += 64) {
    float acc = 0.f;
#pragma unroll 8
    for (int d = 0; d < 128; d++) acc += qsh[wv][d] * ksT[d][jj];
    float sca = acc / sqrtf(128.0f);
    float tch = tanhf(sca / 30.0f) * 30.0f;
    float biasv = -slope * (float)(r - idxs[jj]);
    float val = tch + biasv;
    if (jj == lane) s0 = val; else s1 = val;
  }
  float m = fmaxf(s0, s1);
#pragma unroll
  for (int off = 32; off > 0; off >>= 1) m = fmaxf(m, __shfl_down(m, off));
  m = __shfl(m, 0);
  float e0 = (lane < cnt) ? expf(s0 - m) : 0.f;
  float e1 = (lane + 64 < cnt) ? expf(s1 - m) : 0.f;
  float sum = e0 + e1;
#pragma unroll
  for (int off = 32; off > 0; off >>= 1) sum += __shfl_down(sum, off);
  sum = __shfl(sum, 0);
  float p0 = e0 / sum;
  float p1 = e1 / sum;

  const float* vbase = kv + (size_t)b * T_SEQ * 1024 + 512 + g * HD;
  float y0 = 0.f, y1 = 0.f;
  for (int j = 0; j < cnt; j++) {
    float pj = (j < 64) ? __shfl(p0, j) : __shfl(p1, j - 64);
    const float* vp = vbase + (size_t)idxs[j] * 1024;
    y0 += pj * vp[lane];
    y1 += pj * vp[lane + 64];
  }
  float* op = yg + (size_t)br * 2048 + H * HD;
  op[lane] = y0;
  op[lane + 64] = y1;
}

// ---------------------------------------------------------------------------
// Gate (unchanged).
// ---------------------------------------------------------------------------
__global__ __launch_bounds__(256) void gate_kernel(
    float* __restrict__ yg, const float* __restrict__ gw,
    const float* __restrict__ gb) {
  int blk = blockIdx.x;
  int h = blk & 15;
  int bt0 = (blk >> 4) * 16;
  int tid = threadIdx.x;
  __shared__ float ys[16][128];
  for (int i = tid; i < 16 * 128; i += 256) {
    int rr = i >> 7, d = i & 127;
    ys[rr][d] = yg[(size_t)(bt0 + rr) * 2048 + h * HD + d];
  }
  __syncthreads();
  int e = tid & 127;
  int rblk = tid >> 7;
  const float* gwp = gw + (size_t)h * 16384 + e;
  float acc[8] = {};
  for (int d = 0; d < 128; d++) {
    float wval = gwp[(size_t)d * 128];
#pragma unroll
    for (int k = 0; k < 8; k++) acc[k] += ys[rblk * 8 + k][d] * wval;
  }
  float bb = gb[h * 128 + e];
#pragma unroll
  for (int k = 0; k < 8; k++) {
    int rr = rblk * 8 + k;
    float gate = 1.f / (1.f + expf(-(acc[k] + bb)));
    yg[(size_t)(bt0 + rr) * 2048 + h * HD + e] = ys[rr][e] * gate;
  }
}

// ---------------------------------------------------------------------------
extern "C" void kernel_launch(void* const* d_in, const int* in_sizes, int n_in,
                              void* d_out, int out_size, void* d_ws, size_t ws_size,
                              hipStream_t stream) {
  const float* x      = (const float*)d_in[0];
  const float* w_q    = (const float*)d_in[1];
  const float* b_q    = (const float*)d_in[2];
  const float* w_down = (const float*)d_in[3];
  const float* b_down = (const float*)d_in[4];
  const float* w_up   = (const float*)d_in[5];
  const float* b_up   = (const float*)d_in[6];
  const float* w_o    = (const float*)d_in[7];
  const float* b_o    = (const float*)d_in[8];
  const float* qn_w   = (const float*)d_in[9];
  const float* kn_w   = (const float*)d_in[10];
  const float* gate_w = (const float*)d_in[11];
  const float* gate_b = (const float*)d_in[12];

  // ws layout (float offsets):
  //   kvbuf 0 | yg/dlat 4194304 | tab 12582912 | cnt 12845056(int)
  //   sidx 12849152(int) | qsel 13120000 | [ushorts from 13906432]:
  //   xb/dlatb/ygb (8.39M ushorts; S(one batch, 16.78 MB) aliases this
  //   between up-proj and o-proj) then wT/wupT (4.19M ushorts)   (~81 MB)
  float* ws    = (float*)d_ws;
  float* kvbuf = ws;
  float* yg    = ws + 4194304;
  float* dlat  = yg;                          // dead before attn writes yg
  float* tab   = ws + 12582912;
  int*   cnt   = (int*)(ws + 12845056);
  int*   sidx  = cnt + 4096;
  float* qsel  = ws + 13120000;               // 4096 x 128
  unsigned short* xb  = (unsigned short*)(ws + 13906432);  // 4096x2048 bf16
  unsigned short* dlatb = xb;                 // xb dead after q-proj
  unsigned short* ygb = xb;                   // dead again after up-proj
  unsigned* Sbuf = (unsigned*)xb;             // 2048x2048 u32, per batch
  unsigned short* wT  = xb + 8388608;         // 2048x2048 bf16 [N,K]
  unsigned short* wupT = wT;                  // w_qT dead after q-proj mfma

  float* qbuf = (float*)d_out;                // d_out doubles as q staging
  const int BT = BATCH * T_SEQ;               // 4096

  rope_table_kernel<<<T_SEQ, 64, 0, stream>>>(tab);
  // ---- q-proj (bf16 MFMA) ----
  convert_bf16_kernel<<<8192, 256, 0, stream>>>(x, xb, 2097152);
  transpose_bf16_kernel<<<dim3(64, 64), 256, 0, stream>>>(w_q, wT, 2048, 2048);
  mfma_gemm_bt<<<dim3(16, 32), 256, 0, stream>>>(xb, wT, b_q, qbuf,
                                                 BT, 2048, 2048);
  // ---- exact fp32 selection q: head 0 ----
  sgemm_kernel<<<dim3(2, 64), 256, 0, stream>>>(x, w_q, b_q, qsel,
                                                BT, 128, 2048, 2048, 128);
  // ---- latent down-proj (fp32 exact; feeds selection k) ----
  sgemm_kernel<<<dim3(8, 64), 256, 0, stream>>>(x, w_down, b_down, dlat,
                                                BT, 512, 2048, 512, 512);
  // ---- up-proj: full kv in bf16 MFMA, then exact fp32 cols 0..127 ----
  convert_bf16_kernel<<<2048, 256, 0, stream>>>(dlat, dlatb, 524288);
  transpose_bf16_kernel<<<dim3(32, 16), 256, 0, stream>>>(w_up, wupT,
                                                          512, 1024);
  mfma_gemm_bt<<<dim3(8, 32), 256, 0, stream>>>(dlatb, wupT, b_up, kvbuf,
                                                BT, 1024, 512);
  sgemm_kernel<<<dim3(2, 64), 256, 0, stream>>>(dlat, w_up, b_up, kvbuf,
                                                BT, 128, 512, 1024, 1024);
  // ---- rmsnorm + rope ----
  norm_rope_kernel<<<BT * 16, 128, 0, stream>>>(qbuf, qn_w, tab, 16, 2048);
  norm_rope_kernel<<<BT, 128, 0, stream>>>(qsel, qn_w, tab, 1, 128);
  norm_rope_kernel<<<BT * 4, 128, 0, stream>>>(kvbuf, kn_w, tab, 4, 1024);
  // ---- selection (per batch; S aliases dead xb region) ----
  for (int b = 0; b < BATCH; b++) {
    score_kernel<<<dim3(32, 32), 256, 0, stream>>>(qsel, kvbuf, Sbuf, b);
    select_topk_kernel<<<512, 256, 0, stream>>>(Sbuf, cnt, sidx, b);
  }
  // ---- gathered sparse attention ----
  attn_kernel<<<BT * 4, 256, 0, stream>>>(qbuf, kvbuf, cnt, sidx, yg);
  // ---- gating ----
  gate_kernel<<<(BT / 16) * 16, 256, 0, stream>>>(yg, gate_w, gate_b);
  // ---- o-proj (bf16 MFMA) ----
  convert_bf16_kernel<<<8192, 256, 0, stream>>>(yg, ygb, 2097152);
  transpose_bf16_kernel<<<dim3(64, 64), 256, 0, stream>>>(w_o, wT, 2048, 2048);
  mfma_gemm_bt<<<dim3(16, 32), 256, 0, stream>>>(ygb, wT, b_o, (float*)d_out,
                                                 BT, 2048, 2048);
}

// Round 5
// 985.885 us; speedup vs baseline: 1.5437x; 1.0830x over previous
//
#include <hip/hip_runtime.h>
#include <math.h>

// Problem constants (B=2, T=2048, DIM=2048, HEADS=16, HEAD_DIM=128, N_KV=4,
// LATENT=512, SEL_TOPK=64, SEL_DIM=64, SOFTCAP=30, EPS=1e-6)
#define T_SEQ 2048
#define BATCH 2
#define NHEADS 16
#define HD 128
#define NKV 4

typedef __bf16 bf16x8 __attribute__((ext_vector_type(8)));
typedef float f32x4 __attribute__((ext_vector_type(4)));

__device__ inline unsigned short bf16rne(float f) {
  unsigned u = __float_as_uint(f);
  unsigned r = (u + 0x7FFFu + ((u >> 16) & 1u)) >> 16;
  return (unsigned short)r;
}

__device__ inline float bflo(unsigned u) {          // low bf16 of a dword
  return __uint_as_float(u << 16);
}
__device__ inline float bfhi(unsigned u) {          // high bf16 of a dword
  return __uint_as_float(u & 0xFFFF0000u);
}

__device__ inline void gload_lds16(const void* g, void* l) {
  __builtin_amdgcn_global_load_lds(
      (__attribute__((address_space(1))) void*)const_cast<void*>(g),
      (__attribute__((address_space(3))) void*)l, 16, 0, 0);
}

// monotonic encoding: enc(a) < enc(b) <=> a < b (floats, -inf ok)
#define ENC_NEGINF 0x007FFFFFu
__device__ inline unsigned enc32(float v) {
  unsigned u = __float_as_uint(v);
  return (u & 0x80000000u) ? ~u : (u | 0x80000000u);
}

// ---------------------------------------------------------------------------
// RoPE table: tab[t][i] = (cos, sin), i = pair index 0..63. numpy fp32 op
// order: y=fl32(10000^x) (double pow), inv=1/y (fp32), angle=fl32(t*inv).
// ---------------------------------------------------------------------------
__global__ void rope_table_kernel(float* __restrict__ tab) {
  int t = blockIdx.x;
  int i = threadIdx.x;                 // 0..63
  int j = (2 * i) & 63;
  float y = (float)pow(10000.0, (double)j / 64.0);
  float invf = 1.0f / y;
  float angle = (float)t * invf;
  double a = (double)angle;
  tab[(t * 64 + i) * 2 + 0] = (float)cos(a);
  tab[(t * 64 + i) * 2 + 1] = (float)sin(a);
}

// ---------------------------------------------------------------------------
// RMSNorm (128 dims) + interleaved RoPE, in place.
// ---------------------------------------------------------------------------
__global__ __launch_bounds__(128) void norm_rope_kernel(
    float* __restrict__ base, const float* __restrict__ w,
    const float* __restrict__ tab, int Hloc, int rowStride) {
  int blk = blockIdx.x;
  int h = blk % Hloc;
  int bt = blk / Hloc;
  int t = bt & (T_SEQ - 1);
  float* row = base + (size_t)bt * rowStride + h * HD;
  int d = threadIdx.x;
  float v = row[d];
  __shared__ float red[128];
  red[d] = v * v;
  __syncthreads();
#pragma unroll
  for (int off = 64; off > 0; off >>= 1) {
    if (d < off) red[d] += red[d + off];
    __syncthreads();
  }
  float ssum = red[0];
  __syncthreads();
  float inv = 1.0f / sqrtf(ssum / 128.0f + 1e-6f);
  float xn = v * inv * w[d];
  red[d] = xn;
  __syncthreads();
  int p = d >> 1;
  float c  = tab[(t * 64 + p) * 2 + 0];
  float sn = tab[(t * 64 + p) * 2 + 1];
  float x1 = red[p * 2], x2 = red[p * 2 + 1];
  row[d] = ((d & 1) == 0) ? (x1 * c - x2 * sn) : (x1 * sn + x2 * c);
}

// ---------------------------------------------------------------------------
// fp32 tiled GEMM (exact paths only: qsel head0, dlat, kv cols 0..127):
// C[M,N] = A[M,K] @ W[K,N] + bias. 64x64 tile, BK=16, 4x4 microtile.
// Sequential-k summation order (selection-exactness frozen since round 1).
// ---------------------------------------------------------------------------
#define BKG 16
__global__ __launch_bounds__(256) void sgemm_kernel(
    const float* __restrict__ A, const float* __restrict__ W,
    const float* __restrict__ bias, float* __restrict__ C,
    int M, int N, int K, int ldw, int ldc) {
  __shared__ float As[BKG][68];
  __shared__ float Bs[BKG][68];
  int tid = threadIdx.x;
  int tx = tid & 15;
  int ty = tid >> 4;
  int m0 = blockIdx.y * 64;
  int n0 = blockIdx.x * 64;
  int ar = tid >> 2, ac = (tid & 3) * 4;
  int brr = tid >> 4, bc = (tid & 15) * 4;
  const float* Ap = A + (size_t)(m0 + ar) * K + ac;
  const float* Wp = W + (size_t)brr * ldw + n0 + bc;
  float acc[4][4] = {};
  for (int k0 = 0; k0 < K; k0 += BKG) {
    float4 av = *(const float4*)(Ap + k0);
    float4 wv = *(const float4*)(Wp + (size_t)k0 * ldw);
    As[ac + 0][ar] = av.x; As[ac + 1][ar] = av.y;
    As[ac + 2][ar] = av.z; As[ac + 3][ar] = av.w;
    *(float4*)&Bs[brr][bc] = wv;
    __syncthreads();
#pragma unroll
    for (int kk = 0; kk < BKG; kk++) {
      float4 a = *(const float4*)&As[kk][ty * 4];
      float4 b = *(const float4*)&Bs[kk][tx * 4];
      float aa[4] = {a.x, a.y, a.z, a.w};
      float bb[4] = {b.x, b.y, b.z, b.w};
#pragma unroll
      for (int i = 0; i < 4; i++)
#pragma unroll
        for (int j = 0; j < 4; j++) acc[i][j] += aa[i] * bb[j];
    }
    __syncthreads();
  }
  float4 bv = *(const float4*)&bias[n0 + tx * 4];
  float bb[4] = {bv.x, bv.y, bv.z, bv.w};
#pragma unroll
  for (int i = 0; i < 4; i++) {
    float4 o;
    o.x = acc[i][0] + bb[0];
    o.y = acc[i][1] + bb[1];
    o.z = acc[i][2] + bb[2];
    o.w = acc[i][3] + bb[3];
    *(float4*)&C[(size_t)(m0 + ty * 4 + i) * ldc + n0 + tx * 4] = o;
  }
}

// ---------------------------------------------------------------------------
// bf16 MFMA GEMM: C[M,N] = A[M,K] @ BT[N,K]^T + bias, fp32 accumulate.
// 128x128 tile, BK=64, 4 waves, 16x16x32 MFMA. Fragment-major LDS so
// global_load_lds(16B) stages fragments directly; ds_read_b128 conflict-free.
// ---------------------------------------------------------------------------
__global__ __launch_bounds__(256) void mfma_gemm_bt(
    const unsigned short* __restrict__ A,   // [M,K] bf16
    const unsigned short* __restrict__ BT,  // [N,K] bf16
    const float* __restrict__ bias,         // [N]
    float* __restrict__ C,                  // [M,N] fp32
    int M, int N, int K) {
  __shared__ bf16x8 lA[16][64];
  __shared__ bf16x8 lB[16][64];
  int tid = threadIdx.x;
  int w = tid >> 6, lane = tid & 63;
  int m0 = blockIdx.y * 128, n0 = blockIdx.x * 128;
  int wm = w >> 1, wn = w & 1;
  f32x4 acc[4][4] = {};
  int sr = lane & 15;
  int sk = (lane >> 4) * 8;
  const unsigned short* Abase = A + (size_t)(m0 + sr) * K + sk;
  const unsigned short* Bbase = BT + (size_t)(n0 + sr) * K + sk;

  for (int k0 = 0; k0 < K; k0 += 64) {
    __syncthreads();
#pragma unroll
    for (int c = 0; c < 4; c++) {
      int ch = w * 4 + c;
      int tt = ch >> 1, kk = ch & 1;
      gload_lds16(Abase + (size_t)(tt * 16) * K + k0 + kk * 32, &lA[ch][0]);
      gload_lds16(Bbase + (size_t)(tt * 16) * K + k0 + kk * 32, &lB[ch][0]);
    }
    __syncthreads();
#pragma unroll
    for (int kk = 0; kk < 2; kk++) {
      bf16x8 af[4], bfr[4];
#pragma unroll
      for (int t = 0; t < 4; t++) {
        af[t]  = lA[(wm * 4 + t) * 2 + kk][lane];
        bfr[t] = lB[(wn * 4 + t) * 2 + kk][lane];
      }
#pragma unroll
      for (int i = 0; i < 4; i++)
#pragma unroll
        for (int j = 0; j < 4; j++)
          acc[i][j] = __builtin_amdgcn_mfma_f32_16x16x32_bf16(
              af[i], bfr[j], acc[i][j], 0, 0, 0);
    }
  }
  int col0 = n0 + wn * 64 + (lane & 15);
  int row0 = m0 + wm * 64 + (lane >> 4) * 4;
#pragma unroll
  for (int j = 0; j < 4; j++) {
    float bv = bias[col0 + j * 16];
#pragma unroll
    for (int i = 0; i < 4; i++) {
#pragma unroll
      for (int r = 0; r < 4; r++)
        C[(size_t)(row0 + i * 16 + r) * N + col0 + j * 16] = acc[i][j][r] + bv;
    }
  }
}

// ---------------------------------------------------------------------------
// fp32 -> bf16 flat convert (RNE), 4 elems/thread.
// ---------------------------------------------------------------------------
__global__ __launch_bounds__(256) void convert_bf16_kernel(
    const float* __restrict__ X, unsigned short* __restrict__ Y, int n4) {
  int i = blockIdx.x * 256 + threadIdx.x;
  if (i >= n4) return;
  float4 v = ((const float4*)X)[i];
  ushort4 o;
  o.x = bf16rne(v.x); o.y = bf16rne(v.y);
  o.z = bf16rne(v.z); o.w = bf16rne(v.w);
  ((ushort4*)Y)[i] = o;
}

// ---------------------------------------------------------------------------
// fp32 [K,N] -> bf16 [N,K] transpose-convert, 32x32 LDS tile.
// ---------------------------------------------------------------------------
__global__ __launch_bounds__(256) void transpose_bf16_kernel(
    const float* __restrict__ W, unsigned short* __restrict__ WT,
    int K, int N) {
  __shared__ unsigned short t[32][33];
  int k0 = blockIdx.y * 32, n0 = blockIdx.x * 32;
  int tid = threadIdx.x;
#pragma unroll
  for (int i = 0; i < 4; i++) {
    int idx = tid + i * 256;
    int r = idx >> 5, c = idx & 31;
    t[c][r] = bf16rne(W[(size_t)(k0 + r) * N + n0 + c]);
  }
  __syncthreads();
#pragma unroll
  for (int i = 0; i < 4; i++) {
    int idx = tid + i * 256;
    int r = idx >> 5, c = idx & 31;
    WT[(size_t)(n0 + r) * K + k0 + c] = t[r][c];
  }
}

// ---------------------------------------------------------------------------
// Selection scores: one 64x64 causal tile per block, per batch b.
// S[r][c] = enc32( (q[r,0:64] . k[c,0:64]) * 0.125 ) for c<=r, else NEGINF.
// ---------------------------------------------------------------------------
__global__ __launch_bounds__(256) void score_kernel(
    const float* __restrict__ qsel,   // [BT,128] (normed+roped head 0)
    const float* __restrict__ kv,     // [BT,1024] (post-norm; k head0 = 0:64)
    unsigned* __restrict__ S,         // [2048][2048] for batch b
    int b) {
  int tc = blockIdx.x, tr = blockIdx.y;
  if (tc > tr || tr == 0) return;     // causal; rows 0..63 use early path
  __shared__ float qsT[64][68];
  __shared__ float ksT[64][68];
  int tid = threadIdx.x;
  int r0 = tr * 64, c0 = tc * 64;
#pragma unroll
  for (int u = 0; u < 16; u++) {
    int idx = u * 256 + tid;
    int row = idx >> 6, d = idx & 63;
    qsT[d][row] = qsel[((size_t)(b * T_SEQ + r0 + row)) * 128 + d];
  }
#pragma unroll
  for (int u = 0; u < 16; u++) {
    int idx = u * 256 + tid;
    int c = idx >> 6, d = idx & 63;
    ksT[d][c] = kv[((size_t)(b * T_SEQ + c0 + c)) * 1024 + d];
  }
  __syncthreads();
  int tx = tid & 15, ty = tid >> 4;
  float acc[4][4] = {};
  for (int d = 0; d < 64; d++) {
    float4 qv = *(const float4*)&qsT[d][ty * 4];
    float4 kx = *(const float4*)&ksT[d][tx * 4];
    float qq[4] = {qv.x, qv.y, qv.z, qv.w};
    float kk[4] = {kx.x, kx.y, kx.z, kx.w};
#pragma unroll
    for (int i = 0; i < 4; i++)
#pragma unroll
      for (int j = 0; j < 4; j++) acc[i][j] += qq[i] * kk[j];
  }
#pragma unroll
  for (int i = 0; i < 4; i++) {
    int r = r0 + ty * 4 + i;
    uint4 o;
    int c = c0 + tx * 4;
    o.x = (c + 0 <= r) ? enc32(acc[i][0] * 0.125f) : ENC_NEGINF;
    o.y = (c + 1 <= r) ? enc32(acc[i][1] * 0.125f) : ENC_NEGINF;
    o.z = (c + 2 <= r) ? enc32(acc[i][2] * 0.125f) : ENC_NEGINF;
    o.w = (c + 3 <= r) ? enc32(acc[i][3] * 0.125f) : ENC_NEGINF;
    *(uint4*)&S[(size_t)r * 2048 + c] = o;
  }
}

// ---------------------------------------------------------------------------
// Selection v4 (passed round 4): wave-per-row binary-search threshold +
// ballot compaction; jax.lax.top_k tie order. Per batch b.
// ---------------------------------------------------------------------------
__global__ __launch_bounds__(256) void select_topk_kernel(
    const unsigned* __restrict__ S,   // [2048][2048] batch b
    int* __restrict__ sel_cnt, int* __restrict__ sel_idx, int b) {
  int blk = blockIdx.x;              // 512 blocks of 4 rows
  int r0 = blk * 4;
  int tid = threadIdx.x;

  if (r0 < 64) {                     // rows 0..63: all causal keys selected
    for (int j = 0; j < 4; j++) {
      int r = r0 + j;
      int row = b * T_SEQ + r;
      if (tid == 0) sel_cnt[row] = r + 1;
      for (int c = tid; c <= r; c += 256) sel_idx[row * 66 + c] = c;
    }
    return;
  }

  int wv = tid >> 6, lane = tid & 63;
  int rr = r0 + wv;
  int row = b * T_SEQ + rr;
  int imax = rr >> 6;

  unsigned e[32];
  const unsigned* Sp = S + (size_t)rr * 2048 + lane;
#pragma unroll
  for (int i = 0; i < 32; i++) e[i] = (i <= imax) ? Sp[i * 64] : ENC_NEGINF;

  unsigned t = 0;
  for (int bit = 31; bit >= 0; --bit) {
    unsigned cand = t | (1u << bit);
    int cnt = 0;
#pragma unroll
    for (int i = 0; i < 32; i++) cnt += (e[i] >= cand) ? 1 : 0;
#pragma unroll
    for (int off = 1; off < 64; off <<= 1) cnt += __shfl_xor(cnt, off);
    if (cnt >= 64) t = cand;
  }

  unsigned long long below = (lane == 63) ? 0x7FFFFFFFFFFFFFFFull
                                          : ((1ull << lane) - 1ull);
  bool hasdiag = false;
  int base = 0;
#pragma unroll
  for (int i = 0; i < 32; i++) {
    int c = i * 64 + lane;
    bool wn = (e[i] > t);
    unsigned long long m = __ballot(wn);
    if (wn) {
      int slot = base + (int)__popcll(m & below);
      sel_idx[(size_t)row * 66 + slot] = c;
      if (c == rr) hasdiag = true;
    }
    base += (int)__popcll(m);
  }
  int g = base;
  int need = 64 - g;
  int tb = 0;
#pragma unroll
  for (int i = 0; i < 32; i++) {
    int c = i * 64 + lane;
    bool tie = (e[i] == t);
    unsigned long long m = __ballot(tie);
    int rank = tb + (int)__popcll(m & below);
    if (tie && rank < need) {
      sel_idx[(size_t)row * 66 + g + rank] = c;
      if (c == rr) hasdiag = true;
    }
    tb += (int)__popcll(m);
  }
  unsigned long long hd = __ballot(hasdiag);
  if (lane == 0) {
    sel_cnt[row] = hd ? 64 : 65;
    if (!hd) sel_idx[(size_t)row * 66 + 64] = rr;
  }
}

// ---------------------------------------------------------------------------
// Gathered attention v2 — no K/V LDS staging, barrier-free.
// Block = (b, r, kv-group g); wave wv = local head. Score: lane = key,
// K streamed from global bf16 (L1-shared by the 4 head-waves); q via
// wave-uniform broadcast loads. 65th key via d-parallel shfl reduce.
// PV: p round-trips through a 1KB LDS pbuf (broadcast b128 reads), V rows
// streamed coalesced bf16x2. Only numerics change vs v1: K/V in bf16.
// ---------------------------------------------------------------------------
__global__ __launch_bounds__(256) void attn_kernel(
    const float* __restrict__ q,              // [BT,2048] fp32 normed+roped
    const unsigned short* __restrict__ kvb,   // [BT,1024] bf16 normed+roped
    const int* __restrict__ sel_cnt, const int* __restrict__ sel_idx,
    float* __restrict__ yg) {
  int blk = blockIdx.x;
  int g = blk & 3;
  int br = blk >> 2;               // b*T + r
  int b = br >> 11;
  int r = br & (T_SEQ - 1);
  int tid = threadIdx.x;
  int lane = tid & 63, wv = tid >> 6;
  int H = g * 4 + wv;

  __shared__ float pbuf[4][68];

  int cnt = sel_cnt[br];
  const int* srow = sel_idx + (size_t)br * 66;

  // alibi slope = (2^-0.5)^(H+1), double repeated-multiply then fp32 round
  double sd = 1.0;
  for (int i = 0; i <= H; i++) sd *= 0.70710678118654752440;
  float slope = (float)sd;

  const float* qrow = q + (size_t)br * 2048 + H * HD;

  // ---- scores: key j = lane ----
  int kidx = srow[min(lane, cnt - 1)];
  const uint4* kp = (const uint4*)(kvb + ((size_t)(b * T_SEQ + kidx)) * 1024
                                   + g * HD);
  float acc = 0.f;
#pragma unroll
  for (int dd = 0; dd < 16; dd++) {
    uint4 kb = kp[dd];                        // 8 bf16 dims, scattered rows
    float4 qa = *(const float4*)(qrow + dd * 8);      // uniform broadcast
    float4 qb = *(const float4*)(qrow + dd * 8 + 4);
    acc += qa.x * bflo(kb.x) + qa.y * bfhi(kb.x);
    acc += qa.z * bflo(kb.y) + qa.w * bfhi(kb.y);
    acc += qb.x * bflo(kb.z) + qb.y * bfhi(kb.z);
    acc += qb.z * bflo(kb.w) + qb.w * bfhi(kb.w);
  }
  float sca = acc / sqrtf(128.0f);
  float tch = tanhf(sca / 30.0f) * 30.0f;
  float s = (lane < cnt) ? (tch - slope * (float)(r - kidx)) : -INFINITY;

  // ---- 65th key (always the diagonal when present): d-parallel reduce ----
  float stail = -INFINITY;
  if (cnt == 65) {
    int i64 = srow[64];                      // uniform
    const unsigned* tp = (const unsigned*)(kvb
        + ((size_t)(b * T_SEQ + i64)) * 1024 + g * HD);
    unsigned u = tp[lane];                   // dims 2l, 2l+1 (coalesced)
    float2 qt = *(const float2*)(qrow + 2 * lane);
    float ta = qt.x * bflo(u) + qt.y * bfhi(u);
#pragma unroll
    for (int off = 32; off > 0; off >>= 1) ta += __shfl_xor(ta, off);
    stail = tanhf(ta / sqrtf(128.0f) / 30.0f) * 30.0f
            - slope * (float)(r - i64);
  }

  // ---- softmax (xor reductions -> all lanes) ----
  float m = s;
#pragma unroll
  for (int off = 32; off > 0; off >>= 1) m = fmaxf(m, __shfl_xor(m, off));
  m = fmaxf(m, stail);
  float e = (lane < cnt) ? expf(s - m) : 0.f;
  float sum = e;
#pragma unroll
  for (int off = 32; off > 0; off >>= 1) sum += __shfl_xor(sum, off);
  float et = (cnt == 65) ? expf(stail - m) : 0.f;
  sum += et;
  pbuf[wv][lane] = e / sum;
  if (lane == 0) pbuf[wv][64] = et / sum;
  if (lane >= 1 && lane <= 3) pbuf[wv][64 + lane] = 0.f;   // slots 65..67

  // ---- PV: lane covers dims 2l, 2l+1; p via LDS broadcast b128 ----
  const unsigned short* vbase = kvb + (size_t)b * T_SEQ * 1024 + 512 + g * HD;
  float y0 = 0.f, y1 = 0.f;
  int jmax = (cnt + 3) >> 2;
  for (int j4 = 0; j4 < jmax; j4++) {
    float4 p4 = *(const float4*)&pbuf[wv][j4 * 4];
    float pp[4] = {p4.x, p4.y, p4.z, p4.w};
#pragma unroll
    for (int t = 0; t < 4; t++) {
      int ij = srow[min(j4 * 4 + t, cnt - 1)];           // uniform scalar
      unsigned u = *(const unsigned*)(vbase + (size_t)ij * 1024 + 2 * lane);
      y0 += pp[t] * bflo(u);
      y1 += pp[t] * bfhi(u);
    }
  }
  float2 o;
  o.x = y0;
  o.y = y1;
  *(float2*)(yg + (size_t)br * 2048 + H * HD + 2 * lane) = o;
}

// ---------------------------------------------------------------------------
// Gate (unchanged).
// ---------------------------------------------------------------------------
__global__ __launch_bounds__(256) void gate_kernel(
    float* __restrict__ yg, const float* __restrict__ gw,
    const float* __restrict__ gb) {
  int blk = blockIdx.x;
  int h = blk & 15;
  int bt0 = (blk >> 4) * 16;
  int tid = threadIdx.x;
  __shared__ float ys[16][128];
  for (int i = tid; i < 16 * 128; i += 256) {
    int rr = i >> 7, d = i & 127;
    ys[rr][d] = yg[(size_t)(bt0 + rr) * 2048 + h * HD + d];
  }
  __syncthreads();
  int e = tid & 127;
  int rblk = tid >> 7;
  const float* gwp = gw + (size_t)h * 16384 + e;
  float acc[8] = {};
  for (int d = 0; d < 128; d++) {
    float wval = gwp[(size_t)d * 128];
#pragma unroll
    for (int k = 0; k < 8; k++) acc[k] += ys[rblk * 8 + k][d] * wval;
  }
  float bb = gb[h * 128 + e];
#pragma unroll
  for (int k = 0; k < 8; k++) {
    int rr = rblk * 8 + k;
    float gate = 1.f / (1.f + expf(-(acc[k] + bb)));
    yg[(size_t)(bt0 + rr) * 2048 + h * HD + e] = ys[rr][e] * gate;
  }
}

// ---------------------------------------------------------------------------
extern "C" void kernel_launch(void* const* d_in, const int* in_sizes, int n_in,
                              void* d_out, int out_size, void* d_ws, size_t ws_size,
                              hipStream_t stream) {
  const float* x      = (const float*)d_in[0];
  const float* w_q    = (const float*)d_in[1];
  const float* b_q    = (const float*)d_in[2];
  const float* w_down = (const float*)d_in[3];
  const float* b_down = (const float*)d_in[4];
  const float* w_up   = (const float*)d_in[5];
  const float* b_up   = (const float*)d_in[6];
  const float* w_o    = (const float*)d_in[7];
  const float* b_o    = (const float*)d_in[8];
  const float* qn_w   = (const float*)d_in[9];
  const float* kn_w   = (const float*)d_in[10];
  const float* gate_w = (const float*)d_in[11];
  const float* gate_b = (const float*)d_in[12];

  // ws layout (float offsets):
  //   kvbuf 0 | yg/dlat 4194304 | tab 12582912 | cnt 12845056(int)
  //   sidx 12849152(int) | qsel 13120000 | [ushorts from 13906432]:
  //   xb/dlatb/ygb/Sbuf (8.39M ushorts) then wT region (4.19M ushorts) —
  //   wT region triple-duty: w_qT -> w_upT -> kvb(bf16 kv, alive through
  //   attn) -> w_oT (written only after attn completes; stream-ordered).
  float* ws    = (float*)d_ws;
  float* kvbuf = ws;
  float* yg    = ws + 4194304;
  float* dlat  = yg;                          // dead before attn writes yg
  float* tab   = ws + 12582912;
  int*   cnt   = (int*)(ws + 12845056);
  int*   sidx  = cnt + 4096;
  float* qsel  = ws + 13120000;               // 4096 x 128
  unsigned short* xb  = (unsigned short*)(ws + 13906432);  // 4096x2048 bf16
  unsigned short* dlatb = xb;                 // xb dead after q-proj
  unsigned short* ygb = xb;                   // dead again after up-proj
  unsigned* Sbuf = (unsigned*)xb;             // 2048x2048 u32, per batch
  unsigned short* wT  = xb + 8388608;         // 2048x2048 bf16 [N,K]
  unsigned short* wupT = wT;                  // w_qT dead after q-proj mfma
  unsigned short* kvb  = wT;                  // bf16 kv; wupT dead after up

  float* qbuf = (float*)d_out;                // d_out doubles as q staging
  const int BT = BATCH * T_SEQ;               // 4096

  rope_table_kernel<<<T_SEQ, 64, 0, stream>>>(tab);
  // ---- q-proj (bf16 MFMA) ----
  convert_bf16_kernel<<<8192, 256, 0, stream>>>(x, xb, 2097152);
  transpose_bf16_kernel<<<dim3(64, 64), 256, 0, stream>>>(w_q, wT, 2048, 2048);
  mfma_gemm_bt<<<dim3(16, 32), 256, 0, stream>>>(xb, wT, b_q, qbuf,
                                                 BT, 2048, 2048);
  // ---- exact fp32 selection q: head 0 ----
  sgemm_kernel<<<dim3(2, 64), 256, 0, stream>>>(x, w_q, b_q, qsel,
                                                BT, 128, 2048, 2048, 128);
  // ---- latent down-proj (fp32 exact; feeds selection k) ----
  sgemm_kernel<<<dim3(8, 64), 256, 0, stream>>>(x, w_down, b_down, dlat,
                                                BT, 512, 2048, 512, 512);
  // ---- up-proj: full kv in bf16 MFMA, then exact fp32 cols 0..127 ----
  convert_bf16_kernel<<<2048, 256, 0, stream>>>(dlat, dlatb, 524288);
  transpose_bf16_kernel<<<dim3(32, 16), 256, 0, stream>>>(w_up, wupT,
                                                          512, 1024);
  mfma_gemm_bt<<<dim3(8, 32), 256, 0, stream>>>(dlatb, wupT, b_up, kvbuf,
                                                BT, 1024, 512);
  sgemm_kernel<<<dim3(2, 64), 256, 0, stream>>>(dlat, w_up, b_up, kvbuf,
                                                BT, 128, 512, 1024, 1024);
  // ---- rmsnorm + rope ----
  norm_rope_kernel<<<BT * 16, 128, 0, stream>>>(qbuf, qn_w, tab, 16, 2048);
  norm_rope_kernel<<<BT, 128, 0, stream>>>(qsel, qn_w, tab, 1, 128);
  norm_rope_kernel<<<BT * 4, 128, 0, stream>>>(kvbuf, kn_w, tab, 4, 1024);
  // ---- bf16 kv for attention (into dead wT region) ----
  convert_bf16_kernel<<<4096, 256, 0, stream>>>(kvbuf, kvb, 1048576);
  // ---- selection (per batch; S aliases dead xb region) ----
  for (int b = 0; b < BATCH; b++) {
    score_kernel<<<dim3(32, 32), 256, 0, stream>>>(qsel, kvbuf, Sbuf, b);
    select_topk_kernel<<<512, 256, 0, stream>>>(Sbuf, cnt, sidx, b);
  }
  // ---- gathered sparse attention (bf16 K/V, global-direct) ----
  attn_kernel<<<BT * 4, 256, 0, stream>>>(qbuf, kvb, cnt, sidx, yg);
  // ---- gating ----
  gate_kernel<<<(BT / 16) * 16, 256, 0, stream>>>(yg, gate_w, gate_b);
  // ---- o-proj (bf16 MFMA; wT overwrite is after attn in stream order) ----
  convert_bf16_kernel<<<8192, 256, 0, stream>>>(yg, ygb, 2097152);
  transpose_bf16_kernel<<<dim3(64, 64), 256, 0, stream>>>(w_o, wT, 2048, 2048);
  mfma_gemm_bt<<<dim3(16, 32), 256, 0, stream>>>(ygb, wT, b_o, (float*)d_out,
                                                 BT, 2048, 2048);
}

// Round 6
// 869.345 us; speedup vs baseline: 1.7507x; 1.1341x over previous
//
#include <hip/hip_runtime.h>
#include <math.h>

// Problem constants (B=2, T=2048, DIM=2048, HEADS=16, HEAD_DIM=128, N_KV=4,
// LATENT=512, SEL_TOPK=64, SEL_DIM=64, SOFTCAP=30, EPS=1e-6)
#define T_SEQ 2048
#define BATCH 2
#define NHEADS 16
#define HD 128
#define NKV 4

typedef __bf16 bf16x8 __attribute__((ext_vector_type(8)));
typedef float f32x4 __attribute__((ext_vector_type(4)));

__device__ inline unsigned short bf16rne(float f) {
  unsigned u = __float_as_uint(f);
  unsigned r = (u + 0x7FFFu + ((u >> 16) & 1u)) >> 16;
  return (unsigned short)r;
}

__device__ inline float bflo(unsigned u) {          // low bf16 of a dword
  return __uint_as_float(u << 16);
}
__device__ inline float bfhi(unsigned u) {          // high bf16 of a dword
  return __uint_as_float(u & 0xFFFF0000u);
}

__device__ inline void gload_lds16(const void* g, void* l) {
  __builtin_amdgcn_global_load_lds(
      (__attribute__((address_space(1))) void*)const_cast<void*>(g),
      (__attribute__((address_space(3))) void*)l, 16, 0, 0);
}

// monotonic encoding: enc(a) < enc(b) <=> a < b (floats, -inf ok)
#define ENC_NEGINF 0x007FFFFFu
__device__ inline unsigned enc32(float v) {
  unsigned u = __float_as_uint(v);
  return (u & 0x80000000u) ? ~u : (u | 0x80000000u);
}

// ---------------------------------------------------------------------------
// RoPE table: tab[t][i] = (cos, sin), i = pair index 0..63. numpy fp32 op
// order: y=fl32(10000^x) (double pow), inv=1/y (fp32), angle=fl32(t*inv).
// ---------------------------------------------------------------------------
__global__ void rope_table_kernel(float* __restrict__ tab) {
  int t = blockIdx.x;
  int i = threadIdx.x;                 // 0..63
  int j = (2 * i) & 63;
  float y = (float)pow(10000.0, (double)j / 64.0);
  float invf = 1.0f / y;
  float angle = (float)t * invf;
  double a = (double)angle;
  tab[(t * 64 + i) * 2 + 0] = (float)cos(a);
  tab[(t * 64 + i) * 2 + 1] = (float)sin(a);
}

// ---------------------------------------------------------------------------
// RMSNorm (128 dims) + interleaved RoPE, in place.
// ---------------------------------------------------------------------------
__global__ __launch_bounds__(128) void norm_rope_kernel(
    float* __restrict__ base, const float* __restrict__ w,
    const float* __restrict__ tab, int Hloc, int rowStride) {
  int blk = blockIdx.x;
  int h = blk % Hloc;
  int bt = blk / Hloc;
  int t = bt & (T_SEQ - 1);
  float* row = base + (size_t)bt * rowStride + h * HD;
  int d = threadIdx.x;
  float v = row[d];
  __shared__ float red[128];
  red[d] = v * v;
  __syncthreads();
#pragma unroll
  for (int off = 64; off > 0; off >>= 1) {
    if (d < off) red[d] += red[d + off];
    __syncthreads();
  }
  float ssum = red[0];
  __syncthreads();
  float inv = 1.0f / sqrtf(ssum / 128.0f + 1e-6f);
  float xn = v * inv * w[d];
  red[d] = xn;
  __syncthreads();
  int p = d >> 1;
  float c  = tab[(t * 64 + p) * 2 + 0];
  float sn = tab[(t * 64 + p) * 2 + 1];
  float x1 = red[p * 2], x2 = red[p * 2 + 1];
  row[d] = ((d & 1) == 0) ? (x1 * c - x2 * sn) : (x1 * sn + x2 * c);
}

// ---------------------------------------------------------------------------
// fp32 tiled GEMM (exact paths only: qsel head0, dlat, kv cols 0..127):
// C[M,N] = A[M,K] @ W[K,N] + bias. 64x64 tile, BK=16, 4x4 microtile.
// Sequential-k summation order (selection-exactness frozen since round 1).
// ---------------------------------------------------------------------------
#define BKG 16
__global__ __launch_bounds__(256) void sgemm_kernel(
    const float* __restrict__ A, const float* __restrict__ W,
    const float* __restrict__ bias, float* __restrict__ C,
    int M, int N, int K, int ldw, int ldc) {
  __shared__ float As[BKG][68];
  __shared__ float Bs[BKG][68];
  int tid = threadIdx.x;
  int tx = tid & 15;
  int ty = tid >> 4;
  int m0 = blockIdx.y * 64;
  int n0 = blockIdx.x * 64;
  int ar = tid >> 2, ac = (tid & 3) * 4;
  int brr = tid >> 4, bc = (tid & 15) * 4;
  const float* Ap = A + (size_t)(m0 + ar) * K + ac;
  const float* Wp = W + (size_t)brr * ldw + n0 + bc;
  float acc[4][4] = {};
  for (int k0 = 0; k0 < K; k0 += BKG) {
    float4 av = *(const float4*)(Ap + k0);
    float4 wv = *(const float4*)(Wp + (size_t)k0 * ldw);
    As[ac + 0][ar] = av.x; As[ac + 1][ar] = av.y;
    As[ac + 2][ar] = av.z; As[ac + 3][ar] = av.w;
    *(float4*)&Bs[brr][bc] = wv;
    __syncthreads();
#pragma unroll
    for (int kk = 0; kk < BKG; kk++) {
      float4 a = *(const float4*)&As[kk][ty * 4];
      float4 b = *(const float4*)&Bs[kk][tx * 4];
      float aa[4] = {a.x, a.y, a.z, a.w};
      float bb[4] = {b.x, b.y, b.z, b.w};
#pragma unroll
      for (int i = 0; i < 4; i++)
#pragma unroll
        for (int j = 0; j < 4; j++) acc[i][j] += aa[i] * bb[j];
    }
    __syncthreads();
  }
  float4 bv = *(const float4*)&bias[n0 + tx * 4];
  float bb[4] = {bv.x, bv.y, bv.z, bv.w};
#pragma unroll
  for (int i = 0; i < 4; i++) {
    float4 o;
    o.x = acc[i][0] + bb[0];
    o.y = acc[i][1] + bb[1];
    o.z = acc[i][2] + bb[2];
    o.w = acc[i][3] + bb[3];
    *(float4*)&C[(size_t)(m0 + ty * 4 + i) * ldc + n0 + tx * 4] = o;
  }
}

// ---------------------------------------------------------------------------
// bf16 MFMA GEMM: C[M,N] = A[M,K] @ BT[N,K]^T + bias, fp32 accumulate.
// 128x128 tile, BK=64, 4 waves, 16x16x32 MFMA. Fragment-major LDS so
// global_load_lds(16B) stages fragments directly; ds_read_b128 conflict-free.
// ---------------------------------------------------------------------------
__global__ __launch_bounds__(256) void mfma_gemm_bt(
    const unsigned short* __restrict__ A,   // [M,K] bf16
    const unsigned short* __restrict__ BT,  // [N,K] bf16
    const float* __restrict__ bias,         // [N]
    float* __restrict__ C,                  // [M,N] fp32
    int M, int N, int K) {
  __shared__ bf16x8 lA[16][64];
  __shared__ bf16x8 lB[16][64];
  int tid = threadIdx.x;
  int w = tid >> 6, lane = tid & 63;
  int m0 = blockIdx.y * 128, n0 = blockIdx.x * 128;
  int wm = w >> 1, wn = w & 1;
  f32x4 acc[4][4] = {};
  int sr = lane & 15;
  int sk = (lane >> 4) * 8;
  const unsigned short* Abase = A + (size_t)(m0 + sr) * K + sk;
  const unsigned short* Bbase = BT + (size_t)(n0 + sr) * K + sk;

  for (int k0 = 0; k0 < K; k0 += 64) {
    __syncthreads();
#pragma unroll
    for (int c = 0; c < 4; c++) {
      int ch = w * 4 + c;
      int tt = ch >> 1, kk = ch & 1;
      gload_lds16(Abase + (size_t)(tt * 16) * K + k0 + kk * 32, &lA[ch][0]);
      gload_lds16(Bbase + (size_t)(tt * 16) * K + k0 + kk * 32, &lB[ch][0]);
    }
    __syncthreads();
#pragma unroll
    for (int kk = 0; kk < 2; kk++) {
      bf16x8 af[4], bfr[4];
#pragma unroll
      for (int t = 0; t < 4; t++) {
        af[t]  = lA[(wm * 4 + t) * 2 + kk][lane];
        bfr[t] = lB[(wn * 4 + t) * 2 + kk][lane];
      }
#pragma unroll
      for (int i = 0; i < 4; i++)
#pragma unroll
        for (int j = 0; j < 4; j++)
          acc[i][j] = __builtin_amdgcn_mfma_f32_16x16x32_bf16(
              af[i], bfr[j], acc[i][j], 0, 0, 0);
    }
  }
  int col0 = n0 + wn * 64 + (lane & 15);
  int row0 = m0 + wm * 64 + (lane >> 4) * 4;
#pragma unroll
  for (int j = 0; j < 4; j++) {
    float bv = bias[col0 + j * 16];
#pragma unroll
    for (int i = 0; i < 4; i++) {
#pragma unroll
      for (int r = 0; r < 4; r++)
        C[(size_t)(row0 + i * 16 + r) * N + col0 + j * 16] = acc[i][j][r] + bv;
    }
  }
}

// ---------------------------------------------------------------------------
// fp32 -> bf16 flat convert (RNE), 4 elems/thread.
// ---------------------------------------------------------------------------
__global__ __launch_bounds__(256) void convert_bf16_kernel(
    const float* __restrict__ X, unsigned short* __restrict__ Y, int n4) {
  int i = blockIdx.x * 256 + threadIdx.x;
  if (i >= n4) return;
  float4 v = ((const float4*)X)[i];
  ushort4 o;
  o.x = bf16rne(v.x); o.y = bf16rne(v.y);
  o.z = bf16rne(v.z); o.w = bf16rne(v.w);
  ((ushort4*)Y)[i] = o;
}

// ---------------------------------------------------------------------------
// fp32 [K,N] -> bf16 [N,K] transpose-convert, 32x32 LDS tile.
// ---------------------------------------------------------------------------
__global__ __launch_bounds__(256) void transpose_bf16_kernel(
    const float* __restrict__ W, unsigned short* __restrict__ WT,
    int K, int N) {
  __shared__ unsigned short t[32][33];
  int k0 = blockIdx.y * 32, n0 = blockIdx.x * 32;
  int tid = threadIdx.x;
#pragma unroll
  for (int i = 0; i < 4; i++) {
    int idx = tid + i * 256;
    int r = idx >> 5, c = idx & 31;
    t[c][r] = bf16rne(W[(size_t)(k0 + r) * N + n0 + c]);
  }
  __syncthreads();
#pragma unroll
  for (int i = 0; i < 4; i++) {
    int idx = tid + i * 256;
    int r = idx >> 5, c = idx & 31;
    WT[(size_t)(n0 + r) * K + k0 + c] = t[r][c];
  }
}

// ---------------------------------------------------------------------------
// Selection scores: one 64x64 causal tile per block, per batch b.
// S[r][c] = enc32( (q[r,0:64] . k[c,0:64]) * 0.125 ) for c<=r, else NEGINF.
// ---------------------------------------------------------------------------
__global__ __launch_bounds__(256) void score_kernel(
    const float* __restrict__ qsel,   // [BT,128] (normed+roped head 0)
    const float* __restrict__ kv,     // [BT,1024] (post-norm; k head0 = 0:64)
    unsigned* __restrict__ S,         // [2048][2048] for batch b
    int b) {
  int tc = blockIdx.x, tr = blockIdx.y;
  if (tc > tr || tr == 0) return;     // causal; rows 0..63 use early path
  __shared__ float qsT[64][68];
  __shared__ float ksT[64][68];
  int tid = threadIdx.x;
  int r0 = tr * 64, c0 = tc * 64;
#pragma unroll
  for (int u = 0; u < 16; u++) {
    int idx = u * 256 + tid;
    int row = idx >> 6, d = idx & 63;
    qsT[d][row] = qsel[((size_t)(b * T_SEQ + r0 + row)) * 128 + d];
  }
#pragma unroll
  for (int u = 0; u < 16; u++) {
    int idx = u * 256 + tid;
    int c = idx >> 6, d = idx & 63;
    ksT[d][c] = kv[((size_t)(b * T_SEQ + c0 + c)) * 1024 + d];
  }
  __syncthreads();
  int tx = tid & 15, ty = tid >> 4;
  float acc[4][4] = {};
  for (int d = 0; d < 64; d++) {
    float4 qv = *(const float4*)&qsT[d][ty * 4];
    float4 kx = *(const float4*)&ksT[d][tx * 4];
    float qq[4] = {qv.x, qv.y, qv.z, qv.w};
    float kk[4] = {kx.x, kx.y, kx.z, kx.w};
#pragma unroll
    for (int i = 0; i < 4; i++)
#pragma unroll
      for (int j = 0; j < 4; j++) acc[i][j] += qq[i] * kk[j];
  }
#pragma unroll
  for (int i = 0; i < 4; i++) {
    int r = r0 + ty * 4 + i;
    uint4 o;
    int c = c0 + tx * 4;
    o.x = (c + 0 <= r) ? enc32(acc[i][0] * 0.125f) : ENC_NEGINF;
    o.y = (c + 1 <= r) ? enc32(acc[i][1] * 0.125f) : ENC_NEGINF;
    o.z = (c + 2 <= r) ? enc32(acc[i][2] * 0.125f) : ENC_NEGINF;
    o.w = (c + 3 <= r) ? enc32(acc[i][3] * 0.125f) : ENC_NEGINF;
    *(uint4*)&S[(size_t)r * 2048 + c] = o;
  }
}

// ---------------------------------------------------------------------------
// Selection v4 (passed rounds 4/5): wave-per-row binary-search threshold +
// ballot compaction; jax.lax.top_k tie order. Per batch b.
// ---------------------------------------------------------------------------
__global__ __launch_bounds__(256) void select_topk_kernel(
    const unsigned* __restrict__ S,   // [2048][2048] batch b
    int* __restrict__ sel_cnt, int* __restrict__ sel_idx, int b) {
  int blk = blockIdx.x;              // 512 blocks of 4 rows
  int r0 = blk * 4;
  int tid = threadIdx.x;

  if (r0 < 64) {                     // rows 0..63: all causal keys selected
    for (int j = 0; j < 4; j++) {
      int r = r0 + j;
      int row = b * T_SEQ + r;
      if (tid == 0) sel_cnt[row] = r + 1;
      for (int c = tid; c <= r; c += 256) sel_idx[row * 66 + c] = c;
    }
    return;
  }

  int wv = tid >> 6, lane = tid & 63;
  int rr = r0 + wv;
  int row = b * T_SEQ + rr;
  int imax = rr >> 6;

  unsigned e[32];
  const unsigned* Sp = S + (size_t)rr * 2048 + lane;
#pragma unroll
  for (int i = 0; i < 32; i++) e[i] = (i <= imax) ? Sp[i * 64] : ENC_NEGINF;

  unsigned t = 0;
  for (int bit = 31; bit >= 0; --bit) {
    unsigned cand = t | (1u << bit);
    int cnt = 0;
#pragma unroll
    for (int i = 0; i < 32; i++) cnt += (e[i] >= cand) ? 1 : 0;
#pragma unroll
    for (int off = 1; off < 64; off <<= 1) cnt += __shfl_xor(cnt, off);
    if (cnt >= 64) t = cand;
  }

  unsigned long long below = (lane == 63) ? 0x7FFFFFFFFFFFFFFFull
                                          : ((1ull << lane) - 1ull);
  bool hasdiag = false;
  int base = 0;
#pragma unroll
  for (int i = 0; i < 32; i++) {
    int c = i * 64 + lane;
    bool wn = (e[i] > t);
    unsigned long long m = __ballot(wn);
    if (wn) {
      int slot = base + (int)__popcll(m & below);
      sel_idx[(size_t)row * 66 + slot] = c;
      if (c == rr) hasdiag = true;
    }
    base += (int)__popcll(m);
  }
  int g = base;
  int need = 64 - g;
  int tb = 0;
#pragma unroll
  for (int i = 0; i < 32; i++) {
    int c = i * 64 + lane;
    bool tie = (e[i] == t);
    unsigned long long m = __ballot(tie);
    int rank = tb + (int)__popcll(m & below);
    if (tie && rank < need) {
      sel_idx[(size_t)row * 66 + g + rank] = c;
      if (c == rr) hasdiag = true;
    }
    tb += (int)__popcll(m);
  }
  unsigned long long hd = __ballot(hasdiag);
  if (lane == 0) {
    sel_cnt[row] = hd ? 64 : 65;
    if (!hd) sel_idx[(size_t)row * 66 + 64] = rr;
  }
}

// ---------------------------------------------------------------------------
// Gathered attention v3 — K staged ONCE per block into XOR-swizzled LDS
// (16B chunk p of row j at slot p^(j&15): rows 256B contiguous, 16B aligned,
// ds_read_b128 2-way banked = free). Score: lane = key, K from LDS, q via
// wave-uniform loads. V stays in global (coalesced per-key rows, L1-shared).
// Softmax/PV/tail identical to round 5 (proven). K/V numerics: bf16.
// ---------------------------------------------------------------------------
__global__ __launch_bounds__(256) void attn_kernel(
    const float* __restrict__ q,              // [BT,2048] fp32 normed+roped
    const unsigned short* __restrict__ kvb,   // [BT,1024] bf16 normed+roped
    const int* __restrict__ sel_cnt, const int* __restrict__ sel_idx,
    float* __restrict__ yg) {
  int blk = blockIdx.x;
  int g = blk & 3;
  int br = blk >> 2;               // b*T + r
  int b = br >> 11;
  int r = br & (T_SEQ - 1);
  int tid = threadIdx.x;
  int lane = tid & 63, wv = tid >> 6;
  int H = g * 4 + wv;

  __shared__ unsigned kls[65 * 64];   // 16.6 KB, swizzled K rows
  __shared__ float pbuf[4][68];
  __shared__ int idxs[66];

  int cnt = sel_cnt[br];
  if (tid < 66) idxs[tid] = (tid < cnt) ? sel_idx[(size_t)br * 66 + tid] : 0;
  __syncthreads();

  // ---- cooperative K staging: chunk c = (row, 16B part) ----
  for (int c = tid; c < 65 * 16; c += 256) {
    int row = c >> 4, part = c & 15;
    uint4 kd = make_uint4(0u, 0u, 0u, 0u);
    if (row < cnt) {
      const unsigned short* gp = kvb
          + ((size_t)(b * T_SEQ + idxs[row])) * 1024 + g * HD + part * 8;
      kd = *(const uint4*)gp;
    }
    int slot = part ^ (row & 15);
    *(uint4*)&kls[row * 64 + slot * 4] = kd;
  }
  __syncthreads();

  // alibi slope = (2^-0.5)^(H+1), double repeated-multiply then fp32 round
  double sd = 1.0;
  for (int i = 0; i <= H; i++) sd *= 0.70710678118654752440;
  float slope = (float)sd;

  const float* qrow = q + (size_t)br * 2048 + H * HD;

  // ---- scores: key j = lane, K from swizzled LDS ----
  int kidx = idxs[min(lane, cnt - 1)];
  int swz = lane & 15;
  const unsigned* kr = &kls[lane * 64];
  float acc = 0.f;
#pragma unroll
  for (int dd = 0; dd < 16; dd++) {
    uint4 kb = *(const uint4*)&kr[(dd ^ swz) * 4];
    float4 qa = *(const float4*)(qrow + dd * 8);      // uniform broadcast
    float4 qb = *(const float4*)(qrow + dd * 8 + 4);
    acc += qa.x * bflo(kb.x) + qa.y * bfhi(kb.x);
    acc += qa.z * bflo(kb.y) + qa.w * bfhi(kb.y);
    acc += qb.x * bflo(kb.z) + qb.y * bfhi(kb.z);
    acc += qb.z * bflo(kb.w) + qb.w * bfhi(kb.w);
  }
  float sca = acc / sqrtf(128.0f);
  float tch = tanhf(sca / 30.0f) * 30.0f;
  float s = (lane < cnt) ? (tch - slope * (float)(r - kidx)) : -INFINITY;

  // ---- 65th key (row 64: swizzle key 0 -> linear): d-parallel reduce ----
  float stail = -INFINITY;
  if (cnt == 65) {
    int i64 = idxs[64];                      // uniform
    unsigned u = kls[64 * 64 + lane];        // dims 2l, 2l+1
    float2 qt = *(const float2*)(qrow + 2 * lane);
    float ta = qt.x * bflo(u) + qt.y * bfhi(u);
#pragma unroll
    for (int off = 32; off > 0; off >>= 1) ta += __shfl_xor(ta, off);
    stail = tanhf(ta / sqrtf(128.0f) / 30.0f) * 30.0f
            - slope * (float)(r - i64);
  }

  // ---- softmax (xor reductions -> all lanes) ----
  float m = s;
#pragma unroll
  for (int off = 32; off > 0; off >>= 1) m = fmaxf(m, __shfl_xor(m, off));
  m = fmaxf(m, stail);
  float e = (lane < cnt) ? expf(s - m) : 0.f;
  float sum = e;
#pragma unroll
  for (int off = 32; off > 0; off >>= 1) sum += __shfl_xor(sum, off);
  float et = (cnt == 65) ? expf(stail - m) : 0.f;
  sum += et;
  pbuf[wv][lane] = e / sum;
  if (lane == 0) pbuf[wv][64] = et / sum;
  if (lane >= 1 && lane <= 3) pbuf[wv][64 + lane] = 0.f;   // slots 65..67

  // ---- PV: lane covers dims 2l, 2l+1; V coalesced from global ----
  const unsigned short* vbase = kvb + (size_t)b * T_SEQ * 1024 + 512 + g * HD;
  float y0 = 0.f, y1 = 0.f;
  int jmax = (cnt + 3) >> 2;
  for (int j4 = 0; j4 < jmax; j4++) {
    float4 p4 = *(const float4*)&pbuf[wv][j4 * 4];
    float pp[4] = {p4.x, p4.y, p4.z, p4.w};
#pragma unroll
    for (int t = 0; t < 4; t++) {
      int ij = idxs[min(j4 * 4 + t, cnt - 1)];           // uniform
      unsigned u = *(const unsigned*)(vbase + (size_t)ij * 1024 + 2 * lane);
      y0 += pp[t] * bflo(u);
      y1 += pp[t] * bfhi(u);
    }
  }
  float2 o;
  o.x = y0;
  o.y = y1;
  *(float2*)(yg + (size_t)br * 2048 + H * HD + 2 * lane) = o;
}

// ---------------------------------------------------------------------------
// Gate (unchanged).
// ---------------------------------------------------------------------------
__global__ __launch_bounds__(256) void gate_kernel(
    float* __restrict__ yg, const float* __restrict__ gw,
    const float* __restrict__ gb) {
  int blk = blockIdx.x;
  int h = blk & 15;
  int bt0 = (blk >> 4) * 16;
  int tid = threadIdx.x;
  __shared__ float ys[16][128];
  for (int i = tid; i < 16 * 128; i += 256) {
    int rr = i >> 7, d = i & 127;
    ys[rr][d] = yg[(size_t)(bt0 + rr) * 2048 + h * HD + d];
  }
  __syncthreads();
  int e = tid & 127;
  int rblk = tid >> 7;
  const float* gwp = gw + (size_t)h * 16384 + e;
  float acc[8] = {};
  for (int d = 0; d < 128; d++) {
    float wval = gwp[(size_t)d * 128];
#pragma unroll
    for (int k = 0; k < 8; k++) acc[k] += ys[rblk * 8 + k][d] * wval;
  }
  float bb = gb[h * 128 + e];
#pragma unroll
  for (int k = 0; k < 8; k++) {
    int rr = rblk * 8 + k;
    float gate = 1.f / (1.f + expf(-(acc[k] + bb)));
    yg[(size_t)(bt0 + rr) * 2048 + h * HD + e] = ys[rr][e] * gate;
  }
}

// ---------------------------------------------------------------------------
extern "C" void kernel_launch(void* const* d_in, const int* in_sizes, int n_in,
                              void* d_out, int out_size, void* d_ws, size_t ws_size,
                              hipStream_t stream) {
  const float* x      = (const float*)d_in[0];
  const float* w_q    = (const float*)d_in[1];
  const float* b_q    = (const float*)d_in[2];
  const float* w_down = (const float*)d_in[3];
  const float* b_down = (const float*)d_in[4];
  const float* w_up   = (const float*)d_in[5];
  const float* b_up   = (const float*)d_in[6];
  const float* w_o    = (const float*)d_in[7];
  const float* b_o    = (const float*)d_in[8];
  const float* qn_w   = (const float*)d_in[9];
  const float* kn_w   = (const float*)d_in[10];
  const float* gate_w = (const float*)d_in[11];
  const float* gate_b = (const float*)d_in[12];

  // ws layout (float offsets):
  //   kvbuf 0 | yg/dlat 4194304 | tab 12582912 | cnt 12845056(int)
  //   sidx 12849152(int) | qsel 13120000 | [ushorts from 13906432]:
  //   xb/dlatb/ygb/Sbuf (8.39M ushorts) then wT region (4.19M ushorts) —
  //   wT region triple-duty: w_qT -> w_upT -> kvb(bf16 kv, alive through
  //   attn) -> w_oT (written only after attn completes; stream-ordered).
  float* ws    = (float*)d_ws;
  float* kvbuf = ws;
  float* yg    = ws + 4194304;
  float* dlat  = yg;                          // dead before attn writes yg
  float* tab   = ws + 12582912;
  int*   cnt   = (int*)(ws + 12845056);
  int*   sidx  = cnt + 4096;
  float* qsel  = ws + 13120000;               // 4096 x 128
  unsigned short* xb  = (unsigned short*)(ws + 13906432);  // 4096x2048 bf16
  unsigned short* dlatb = xb;                 // xb dead after q-proj
  unsigned short* ygb = xb;                   // dead again after up-proj
  unsigned* Sbuf = (unsigned*)xb;             // 2048x2048 u32, per batch
  unsigned short* wT  = xb + 8388608;         // 2048x2048 bf16 [N,K]
  unsigned short* wupT = wT;                  // w_qT dead after q-proj mfma
  unsigned short* kvb  = wT;                  // bf16 kv; wupT dead after up

  float* qbuf = (float*)d_out;                // d_out doubles as q staging
  const int BT = BATCH * T_SEQ;               // 4096

  rope_table_kernel<<<T_SEQ, 64, 0, stream>>>(tab);
  // ---- q-proj (bf16 MFMA) ----
  convert_bf16_kernel<<<8192, 256, 0, stream>>>(x, xb, 2097152);
  transpose_bf16_kernel<<<dim3(64, 64), 256, 0, stream>>>(w_q, wT, 2048, 2048);
  mfma_gemm_bt<<<dim3(16, 32), 256, 0, stream>>>(xb, wT, b_q, qbuf,
                                                 BT, 2048, 2048);
  // ---- exact fp32 selection q: head 0 ----
  sgemm_kernel<<<dim3(2, 64), 256, 0, stream>>>(x, w_q, b_q, qsel,
                                                BT, 128, 2048, 2048, 128);
  // ---- latent down-proj (fp32 exact; feeds selection k) ----
  sgemm_kernel<<<dim3(8, 64), 256, 0, stream>>>(x, w_down, b_down, dlat,
                                                BT, 512, 2048, 512, 512);
  // ---- up-proj: full kv in bf16 MFMA, then exact fp32 cols 0..127 ----
  convert_bf16_kernel<<<2048, 256, 0, stream>>>(dlat, dlatb, 524288);
  transpose_bf16_kernel<<<dim3(32, 16), 256, 0, stream>>>(w_up, wupT,
                                                          512, 1024);
  mfma_gemm_bt<<<dim3(8, 32), 256, 0, stream>>>(dlatb, wupT, b_up, kvbuf,
                                                BT, 1024, 512);
  sgemm_kernel<<<dim3(2, 64), 256, 0, stream>>>(dlat, w_up, b_up, kvbuf,
                                                BT, 128, 512, 1024, 1024);
  // ---- rmsnorm + rope ----
  norm_rope_kernel<<<BT * 16, 128, 0, stream>>>(qbuf, qn_w, tab, 16, 2048);
  norm_rope_kernel<<<BT, 128, 0, stream>>>(qsel, qn_w, tab, 1, 128);
  norm_rope_kernel<<<BT * 4, 128, 0, stream>>>(kvbuf, kn_w, tab, 4, 1024);
  // ---- bf16 kv for attention (into dead wT region) ----
  convert_bf16_kernel<<<4096, 256, 0, stream>>>(kvbuf, kvb, 1048576);
  // ---- selection (per batch; S aliases dead xb region) ----
  for (int b = 0; b < BATCH; b++) {
    score_kernel<<<dim3(32, 32), 256, 0, stream>>>(qsel, kvbuf, Sbuf, b);
    select_topk_kernel<<<512, 256, 0, stream>>>(Sbuf, cnt, sidx, b);
  }
  // ---- gathered sparse attention (bf16 K/V, K LDS-staged once/block) ----
  attn_kernel<<<BT * 4, 256, 0, stream>>>(qbuf, kvb, cnt, sidx, yg);
  // ---- gating ----
  gate_kernel<<<(BT / 16) * 16, 256, 0, stream>>>(yg, gate_w, gate_b);
  // ---- o-proj (bf16 MFMA; wT overwrite is after attn in stream order) ----
  convert_bf16_kernel<<<8192, 256, 0, stream>>>(yg, ygb, 2097152);
  transpose_bf16_kernel<<<dim3(64, 64), 256, 0, stream>>>(w_o, wT, 2048, 2048);
  mfma_gemm_bt<<<dim3(16, 32), 256, 0, stream>>>(ygb, wT, b_o, (float*)d_out,
                                                 BT, 2048, 2048);
}